// Round 12
// baseline (458.185 us; speedup 1.0000x reference)
//
#include <hip/hip_runtime.h>
#include <math.h>

#define THREADS 256
#define SB 2048           // blocks for hist/scatter passes (chunked edge ranges)
#define BSH 8             // bucket shift: 256 nodes per bucket
#define BSZ 256
#define BMSK 255
#define SEG 1024          // edges per scatter segment (4 per thread)
#define DM 8              // degred split factor
#define RC 20             // nodesort register-cache records per thread

// ---------------------------------------------------------------------------
// Per-block LDS histograms over node buckets (bucket = 256 nodes).
__global__ void hist_kernel(const int* __restrict__ row, const int* __restrict__ col,
                            int* __restrict__ TU, int E, int NB, int chunk) {
    extern __shared__ int sh[];
    int t = threadIdx.x, b = blockIdx.x;
    for (int k = t; k < 2 * NB; k += THREADS) sh[k] = 0;
    __syncthreads();
    int lo = b * chunk;
    int hi = min(lo + chunk, E);
    for (int e = lo + t; e < hi; e += THREADS) {
        int r = row[e], c = col[e];
        if (r != c) {
            atomicAdd(&sh[r >> BSH], 1);
            atomicAdd(&sh[NB + (c >> BSH)], 1);
        }
    }
    __syncthreads();
    for (int k = t; k < 2 * NB; k += THREADS) TU[k * SB + b] = sh[k];
}

// ---------------------------------------------------------------------------
// Exclusive scan, 2048 entries per block (8 serial per thread + block scan).
__global__ void scan1_kernel(int* __restrict__ data, int* __restrict__ bsum, int n) {
    __shared__ int s[256];
    int t = threadIdx.x;
    int base = blockIdx.x * 2048 + t * 8;
    int a[8];
    int tsum = 0;
#pragma unroll
    for (int j = 0; j < 8; ++j) {
        a[j] = (base + j < n) ? data[base + j] : 0;
        tsum += a[j];
    }
    s[t] = tsum;
    __syncthreads();
    for (int d = 1; d < 256; d <<= 1) {
        int xv = (t >= d) ? s[t - d] : 0;
        __syncthreads();
        s[t] += xv;
        __syncthreads();
    }
    int run = s[t] - tsum;
#pragma unroll
    for (int j = 0; j < 8; ++j) {
        if (base + j < n) data[base + j] = run;
        run += a[j];
    }
    if (t == 255) bsum[blockIdx.x] = s[255];
}

__global__ void scan2_kernel(const int* __restrict__ bsum, int* __restrict__ boff, int nb) {
    __shared__ int s[1024];
    int t = threadIdx.x;
    int v = (t < nb) ? bsum[t] : 0;
    s[t] = v;
    __syncthreads();
    for (int d = 1; d < 1024; d <<= 1) {
        int xv = (t >= d) ? s[t - d] : 0;
        __syncthreads();
        s[t] += xv;
        __syncthreads();
    }
    if (t < nb) boff[t] = s[t] - v;
    if (t == nb - 1) boff[nb] = s[t];            // grand total
}

__global__ void scan3_kernel(int* __restrict__ data, const int* __restrict__ boff,
                             int n, int nbk) {
    int i = blockIdx.x * blockDim.x + threadIdx.x;
    if (i < n) data[i] += boff[i >> 11];
    else if (i == n) data[n] = boff[nbk];        // append grand total
}

// ---------------------------------------------------------------------------
// Scatter with segment-local counting sort; SoA LDS staging, ~30KB LDS.
__global__ void scatter_kernel(const int* __restrict__ row, const int* __restrict__ col,
                               const float* __restrict__ ew,
                               const int* __restrict__ TU, int2* __restrict__ rec,
                               int E, int NB, int chunk) {
    extern __shared__ int shl[];
    const int nb2 = 2 * NB;
    int* skey  = shl;                                          // [2*SEG]
    int* sval  = skey + 2 * SEG;                               // [2*SEG]
    int* cur   = sval + 2 * SEG;                               // [nb2]
    int* sbase = cur + nb2;                                    // [nb2]
    int* scur  = sbase + nb2;                                  // [nb2]
    int* stmp  = scur + nb2;                                   // [256]
    unsigned short* bid = (unsigned short*)(stmp + 256);       // [2*SEG]

    int t = threadIdx.x, b = blockIdx.x;
    for (int k = t; k < nb2; k += THREADS) cur[k] = TU[k * SB + b];
    int lo = b * chunk;
    int hi = min(lo + chunk, E);

    for (int slo = lo; slo < hi; slo += SEG) {
        int scount = min(SEG, hi - slo);
        for (int k = t; k < nb2; k += THREADS) sbase[k] = 0;
        __syncthreads();

        int er[4], ec[4];
        float ewv[4];
#pragma unroll
        for (int j = 0; j < 4; ++j) {
            er[j] = -1;
            int e = slo + j * THREADS + t;
            if (e < slo + scount) {
                int r = row[e], c = col[e];
                if (r != c) {
                    er[j] = r; ec[j] = c; ewv[j] = ew[e];
                    atomicAdd(&sbase[r >> BSH], 1);
                    atomicAdd(&sbase[NB + (c >> BSH)], 1);
                }
            }
        }
        __syncthreads();

        // exclusive scan of nb2 per-bucket counts (4 serial + 256 block scan)
        int b4 = t * 4;
        int a0 = (b4 + 0 < nb2) ? sbase[b4 + 0] : 0;
        int a1 = (b4 + 1 < nb2) ? sbase[b4 + 1] : 0;
        int a2 = (b4 + 2 < nb2) ? sbase[b4 + 2] : 0;
        int a3 = (b4 + 3 < nb2) ? sbase[b4 + 3] : 0;
        int tsum = a0 + a1 + a2 + a3;
        stmp[t] = tsum;
        __syncthreads();
        for (int d = 1; d < 256; d <<= 1) {
            int xv = (t >= d) ? stmp[t - d] : 0;
            __syncthreads();
            stmp[t] += xv;
            __syncthreads();
        }
        int excl = stmp[t] - tsum;
        int total = stmp[255];
        __syncthreads();
        if (b4 + 0 < nb2) { sbase[b4 + 0] = excl;                scur[b4 + 0] = excl; }
        if (b4 + 1 < nb2) { sbase[b4 + 1] = excl + a0;           scur[b4 + 1] = excl + a0; }
        if (b4 + 2 < nb2) { sbase[b4 + 2] = excl + a0 + a1;      scur[b4 + 2] = excl + a0 + a1; }
        if (b4 + 3 < nb2) { sbase[b4 + 3] = excl + a0 + a1 + a2; scur[b4 + 3] = excl + a0 + a1 + a2; }
        __syncthreads();

        // ranked placement into bucket-ordered SoA staging
#pragma unroll
        for (int j = 0; j < 4; ++j) {
            if (er[j] >= 0) {
                int r = er[j], c = ec[j];
                int wbits = __float_as_int(ewv[j]);
                int k1 = r >> BSH;
                int p1 = atomicAdd(&scur[k1], 1);
                skey[p1] = r & BMSK;
                sval[p1] = wbits;
                bid[p1] = (unsigned short)k1;
                int k2 = NB + (c >> BSH);
                int p2 = atomicAdd(&scur[k2], 1);
                skey[p2] = (r << BSH) | (c & BMSK);
                sval[p2] = wbits;
                bid[p2] = (unsigned short)k2;
            }
        }
        __syncthreads();

        // cooperative dense write-out (consecutive lanes -> consecutive addrs)
        for (int j = t; j < total; j += THREADS) {
            int k = bid[j];
            rec[cur[k] + (j - sbase[k])] = make_int2(skey[j], sval[j]);
        }
        __syncthreads();

        for (int k = t; k < nb2; k += THREADS) cur[k] += scur[k] - sbase[k];
        __syncthreads();
    }
}

// ---------------------------------------------------------------------------
// deg partials over ROW half: grid = NB*DM, 256-slot LDS acc, plain writes.
__global__ void degred_kernel(const int2* __restrict__ rec, const int* __restrict__ TU,
                              float* __restrict__ pdeg) {
    __shared__ float acc[BSZ];
    int t = threadIdx.x;
    int bk = blockIdx.x / DM, m = blockIdx.x % DM;
    acc[t] = 0.f;
    __syncthreads();
    int s = TU[bk * SB];
    int e2 = TU[(bk + 1) * SB];
    int len = e2 - s;
    int lo = s + (int)((long long)len * m / DM);
    int hi = s + (int)((long long)len * (m + 1) / DM);
    int i = lo + t;
    for (; i + 3 * THREADS < hi; i += 4 * THREADS) {
        long long v0 = __builtin_nontemporal_load((const long long*)(rec + i));
        long long v1 = __builtin_nontemporal_load((const long long*)(rec + i + THREADS));
        long long v2 = __builtin_nontemporal_load((const long long*)(rec + i + 2 * THREADS));
        long long v3 = __builtin_nontemporal_load((const long long*)(rec + i + 3 * THREADS));
        atomicAdd(&acc[(int)(v0 & 0xffffffffLL)], __int_as_float((int)(v0 >> 32)));
        atomicAdd(&acc[(int)(v1 & 0xffffffffLL)], __int_as_float((int)(v1 >> 32)));
        atomicAdd(&acc[(int)(v2 & 0xffffffffLL)], __int_as_float((int)(v2 >> 32)));
        atomicAdd(&acc[(int)(v3 & 0xffffffffLL)], __int_as_float((int)(v3 >> 32)));
    }
    for (; i < hi; i += THREADS) {
        int2 p = rec[i];
        atomicAdd(&acc[p.x], __int_as_float(p.y));
    }
    __syncthreads();
    pdeg[(size_t)(bk * DM + m) * BSZ + t] = acc[t];
}

// ---------------------------------------------------------------------------
// init (fused deg-partial reduce): dis = rsqrt(sum pdeg); Tx0 = x[:, :2];
// outacc = Tx0 @ Wc[0].
__global__ void init_kernel(const float* __restrict__ x, const float* __restrict__ pdeg,
                            float* __restrict__ dis, float2* __restrict__ tx0,
                            float2* __restrict__ outacc, const float* __restrict__ Wc,
                            int N) {
    int i = blockIdx.x * blockDim.x + threadIdx.x;
    if (i >= N) return;
    int bk = i >> BSH, li = i & BMSK;
    const float* src = pdeg + (size_t)bk * DM * BSZ + li;
    float d = 0.f;
    for (int m = 0; m < DM; ++m) d += src[(size_t)m * BSZ];
    dis[i] = (d > 0.f) ? rsqrtf(d) : 0.f;
    float x0 = x[3 * i + 0];
    float x1 = x[3 * i + 1];
    tx0[i] = make_float2(x0, x1);
    outacc[i] = make_float2(x0 * Wc[0] + x1 * Wc[2],
                            x0 * Wc[1] + x1 * Wc[3]);
}

// ---------------------------------------------------------------------------
// Node-level sort of the COL half + norm baking -> per-node CSR.
// One 1024-thread block per col bucket; first RC*1024 records are cached in
// registers (single HBM read), overflow re-read. Sorted {r_global, norm}
// records land in the row-half region of rec (dead after degred).
__global__ void nodesort_kernel(const int2* __restrict__ rec, const int* __restrict__ TU,
                                const float* __restrict__ dis,
                                int2* __restrict__ srec, int* __restrict__ rowstart,
                                int NB, int N) {
    __shared__ int cnt[BSZ], cur[BSZ], stmp[BSZ];
    __shared__ float disc[BSZ];
    int t = threadIdx.x, bk = blockIdx.x;
    int colbase = TU[NB * SB];
    if (t < BSZ) {
        cnt[t] = 0;
        int node = (bk << BSH) + t;
        disc[t] = (node < N) ? dis[node] : 0.f;
    }
    __syncthreads();
    int s = TU[(NB + bk) * SB];
    int e = TU[(NB + bk + 1) * SB];

    int2 rr[RC];
    int nr = 0;
#pragma unroll
    for (int j = 0; j < RC; ++j) {
        int i = s + j * 1024 + t;
        if (i < e) {
            rr[j] = rec[i];
            atomicAdd(&cnt[rr[j].x & BMSK], 1);
            nr = j + 1;
        }
    }
    for (int i = s + RC * 1024 + t; i < e; i += 1024)
        atomicAdd(&cnt[rec[i].x & BMSK], 1);
    __syncthreads();

    if (t < BSZ) stmp[t] = cnt[t];
    __syncthreads();
    for (int d = 1; d < BSZ; d <<= 1) {
        int xv = (t >= d && t < BSZ) ? stmp[t - d] : 0;
        __syncthreads();
        if (t < BSZ) stmp[t] += xv;
        __syncthreads();
    }
    if (t < BSZ) {
        int g = (s - colbase) + stmp[t] - cnt[t];
        cur[t] = g;
        rowstart[(bk << BSH) + t] = g;
        if (bk == NB - 1 && t == 0) rowstart[NB << BSH] = e - colbase;
    }
    __syncthreads();

    for (int j = 0; j < nr; ++j) {
        int2 p = rr[j];
        int cl = p.x & BMSK;
        int r = ((unsigned)p.x) >> BSH;
        float w = -dis[r] * __int_as_float(p.y) * disc[cl];
        int pos = atomicAdd(&cur[cl], 1);
        srec[pos] = make_int2(r, __float_as_int(w));
    }
    for (int i = s + RC * 1024 + t; i < e; i += 1024) {
        int2 p = rec[i];
        int cl = p.x & BMSK;
        int r = ((unsigned)p.x) >> BSH;
        float w = -dis[r] * __int_as_float(p.y) * disc[cl];
        int pos = atomicAdd(&cur[cl], 1);
        srec[pos] = make_int2(r, __float_as_int(w));
    }
}

// ---------------------------------------------------------------------------
// Propagation with fused Chebyshev update: 16 lanes per node, 2-record unroll
// (dual accumulators, nontemporal record stream), width-16 shuffle reduce.
__global__ void gather_kernel(const int2* __restrict__ srec, const int* __restrict__ rowstart,
                              const float2* __restrict__ h, const float2* __restrict__ tx0,
                              float2* __restrict__ vout, float2* __restrict__ outacc,
                              const float* __restrict__ Wc, int k, int N) {
    int g = blockIdx.x * (THREADS / 16) + (threadIdx.x >> 4);
    int lane = threadIdx.x & 15;
    if (g >= N) return;
    int s = rowstart[g];
    int e = rowstart[g + 1];
    float sx0 = 0.f, sy0 = 0.f, sx1 = 0.f, sy1 = 0.f;
    int i = s + lane;
    for (; i + 16 < e; i += 32) {
        long long v0 = __builtin_nontemporal_load((const long long*)(srec + i));
        long long v1 = __builtin_nontemporal_load((const long long*)(srec + i + 16));
        int   r0 = (int)(v0 & 0xffffffffLL);
        float w0 = __int_as_float((int)(v0 >> 32));
        int   r1 = (int)(v1 & 0xffffffffLL);
        float w1 = __int_as_float((int)(v1 >> 32));
        float2 h0 = h[r0];
        float2 h1 = h[r1];
        sx0 = fmaf(w0, h0.x, sx0); sy0 = fmaf(w0, h0.y, sy0);
        sx1 = fmaf(w1, h1.x, sx1); sy1 = fmaf(w1, h1.y, sy1);
    }
    if (i < e) {
        int2 p = srec[i];
        float2 hv = h[p.x];
        float w = __int_as_float(p.y);
        sx0 = fmaf(w, hv.x, sx0); sy0 = fmaf(w, hv.y, sy0);
    }
    float sx = sx0 + sx1, sy = sy0 + sy1;
    for (int off = 8; off > 0; off >>= 1) {
        sx += __shfl_down(sx, off, 16);
        sy += __shfl_down(sy, off, 16);
    }
    if (lane == 0) {
        float2 v = make_float2(sx, sy);
        if (tx0) {
            float2 tv = tx0[g];
            v.x = 2.f * v.x - tv.x;
            v.y = 2.f * v.y - tv.y;
        }
        vout[g] = v;
        float2 o = outacc[g];
        o.x += v.x * Wc[4 * k + 0] + v.y * Wc[4 * k + 2];
        o.y += v.x * Wc[4 * k + 1] + v.y * Wc[4 * k + 3];
        outacc[g] = o;
    }
}

// ---------------------------------------------------------------------------
// Full-atomic fallback kernels (only if workspace is too small).
__global__ void zero_kernel(float* __restrict__ p, int n) {
    int i = blockIdx.x * blockDim.x + threadIdx.x;
    if (i < n) p[i] = 0.f;
}
__global__ void zerof2_kernel(float2* __restrict__ p, int n) {
    int i = blockIdx.x * blockDim.x + threadIdx.x;
    if (i < n) p[i] = make_float2(0.f, 0.f);
}
__global__ void deg_at_kernel(const int* __restrict__ row, const int* __restrict__ col,
                              const float* __restrict__ ew, float* __restrict__ deg, int E) {
    int e = blockIdx.x * blockDim.x + threadIdx.x;
    if (e >= E) return;
    int r = row[e], c = col[e];
    if (r != c) atomicAdd(&deg[r], ew[e]);
}
__global__ void init_at_kernel(const float* __restrict__ x, float* __restrict__ deg,
                               float2* __restrict__ tx0, float2* __restrict__ outacc,
                               const float* __restrict__ Wc, int N) {
    int i = blockIdx.x * blockDim.x + threadIdx.x;
    if (i >= N) return;
    float d = deg[i];
    deg[i] = (d > 0.f) ? rsqrtf(d) : 0.f;
    float x0 = x[3 * i + 0];
    float x1 = x[3 * i + 1];
    tx0[i] = make_float2(x0, x1);
    outacc[i] = make_float2(x0 * Wc[0] + x1 * Wc[2],
                            x0 * Wc[1] + x1 * Wc[3]);
}
__global__ void prop_kernel(const int* __restrict__ row, const int* __restrict__ col,
                            const float* __restrict__ ew, const float* __restrict__ dis,
                            const float2* __restrict__ h, float2* __restrict__ o, int E) {
    int e = blockIdx.x * blockDim.x + threadIdx.x;
    if (e >= E) return;
    int r = row[e], c = col[e];
    if (r == c) return;
    float w = -dis[r] * ew[e] * dis[c];
    if (w == 0.f) return;
    float2 hv = h[r];
    atomicAdd(&o[c].x, w * hv.x);
    atomicAdd(&o[c].y, w * hv.y);
}
__global__ void cheb_at_kernel(float2* __restrict__ raw, const float2* __restrict__ tx0,
                               float2* __restrict__ outacc, const float* __restrict__ Wc,
                               int k, int N) {
    int i = blockIdx.x * blockDim.x + threadIdx.x;
    if (i >= N) return;
    float2 v = raw[i];
    if (tx0) {
        float2 t = tx0[i];
        v.x = 2.f * v.x - t.x;
        v.y = 2.f * v.y - t.y;
        raw[i] = v;
    }
    float2 o = outacc[i];
    o.x += v.x * Wc[4 * k + 0] + v.y * Wc[4 * k + 2];
    o.y += v.x * Wc[4 * k + 1] + v.y * Wc[4 * k + 3];
    outacc[i] = o;
}

// ---------------------------------------------------------------------------
// Fused epilogue (3 kernels): per-block (max, sum-of-exp) via LSE rescale.
__global__ void u_ms_kernel(const float* __restrict__ x, const float2* __restrict__ outacc,
                            const float* __restrict__ cb, const float* __restrict__ W,
                            const float* __restrict__ b, float* __restrict__ U,
                            float* __restrict__ part2, int N) {
    __shared__ float sm[THREADS / 64];
    __shared__ float bmax;
    int i = blockIdx.x * blockDim.x + threadIdx.x;
    int t = threadIdx.x;
    float u = -INFINITY;
    if (i < N) {
        float2 o = outacc[i];
        float h0 = fmaxf(o.x + cb[0], 0.f);
        float h1 = fmaxf(o.y + cb[1], 0.f);
        u = x[3 * i + 2] * W[0] + h0 * W[1] + h1 * W[2] + b[0];
        U[i] = u;
    }
    float mv = u;
    for (int off = 32; off > 0; off >>= 1) mv = fmaxf(mv, __shfl_down(mv, off));
    if ((t & 63) == 0) sm[t >> 6] = mv;
    __syncthreads();
    if (t == 0) {
        float m = sm[0];
        for (int w = 1; w < THREADS / 64; ++w) m = fmaxf(m, sm[w]);
        bmax = m;
    }
    __syncthreads();
    float bm = bmax;
    float e = (i < N) ? expf(u - bm) : 0.f;
    for (int off = 32; off > 0; off >>= 1) e += __shfl_down(e, off);
    __syncthreads();
    if ((t & 63) == 0) sm[t >> 6] = e;
    __syncthreads();
    if (t == 0) {
        float s = sm[0];
        for (int w = 1; w < THREADS / 64; ++w) s += sm[w];
        part2[2 * blockIdx.x]     = bm;
        part2[2 * blockIdx.x + 1] = s;
    }
}

__global__ void red_ms_kernel(const float* __restrict__ part2, int n,
                              float* __restrict__ scal) {
    __shared__ float sm[16];
    __shared__ float gmax;
    int t = threadIdx.x;
    float m = -INFINITY;
    for (int i = t; i < n; i += blockDim.x) m = fmaxf(m, part2[2 * i]);
    for (int off = 32; off > 0; off >>= 1) m = fmaxf(m, __shfl_down(m, off));
    int wid = t >> 6;
    if ((t & 63) == 0) sm[wid] = m;
    __syncthreads();
    if (t == 0) {
        float r = sm[0];
        int nw = blockDim.x >> 6;
        for (int w = 1; w < nw; ++w) r = fmaxf(r, sm[w]);
        gmax = r;
    }
    __syncthreads();
    float M = gmax;
    float s = 0.f;
    for (int i = t; i < n; i += blockDim.x) s += part2[2 * i + 1] * expf(part2[2 * i] - M);
    for (int off = 32; off > 0; off >>= 1) s += __shfl_down(s, off);
    __syncthreads();
    if ((t & 63) == 0) sm[wid] = s;
    __syncthreads();
    if (t == 0) {
        float r = sm[0];
        int nw = blockDim.x >> 6;
        for (int w = 1; w < nw; ++w) r += sm[w];
        scal[0] = M;
        scal[1] = 1.f / r;
    }
}

__global__ void out_kernel(const float* __restrict__ U, const float* __restrict__ scal,
                           float* __restrict__ out, int N) {
    int i = blockIdx.x * blockDim.x + threadIdx.x;
    if (i < N) out[i] = expf(U[i] - scal[0]) * scal[1];
}

// ---------------------------------------------------------------------------
extern "C" void kernel_launch(void* const* d_in, const int* in_sizes, int n_in,
                              void* d_out, int out_size, void* d_ws, size_t ws_size,
                              hipStream_t stream) {
    (void)n_in; (void)out_size;
    const float* x    = (const float*)d_in[0];
    const int*   eidx = (const int*)d_in[1];     // int32 per harness contract
    const float* ew   = (const float*)d_in[2];
    const float* Wc   = (const float*)d_in[3];
    const float* cb   = (const float*)d_in[4];
    const float* W    = (const float*)d_in[5];
    const float* b    = (const float*)d_in[6];
    float*       out  = (float*)d_out;

    const int N = in_sizes[0] / 3;
    const int E = in_sizes[2];
    const int K = in_sizes[3] / 4;
    const int* row = eidx;
    const int* col = eidx + E;

    const int NB    = (N + BMSK) >> BSH;         // 256-node buckets
    const int nb2   = 2 * NB;
    const int n2    = nb2 * SB;                  // unified count-table length
    const int nblk  = (n2 + 2047) / 2048;        // scan1 blocks (2048/block)
    const int chunk = (E + SB - 1) / SB;
    const int Npad  = NB << BSH;

    char* ws = (char*)d_ws;
    size_t off = 0;
    auto take = [&](size_t bytes) -> void* {
        void* p = ws + off;
        off = (off + bytes + 255) & ~(size_t)255;
        return p;
    };

    float*  dis      = (float*)take((size_t)N * 4);
    float2* A        = (float2*)take((size_t)N * 8);
    float2* B        = (float2*)take((size_t)N * 8);
    float2* C        = (float2*)take((size_t)N * 8);
    float2* outacc   = (float2*)take((size_t)N * 8);
    float*  U        = (float*)take((size_t)N * 4);
    float*  part     = (float*)take(8192 * 4);
    float*  scal     = (float*)take(64 * 4);
    int*    TU       = (int*)take((size_t)(n2 + 1) * 4);
    int*    bsum     = (int*)take(1024 * 4);
    int*    boff     = (int*)take(1025 * 4);
    int*    rowstart = (int*)take((size_t)(Npad + 1) * 4);
    float*  pdeg     = (float*)take((size_t)NB * DM * BSZ * 4);
    int2*   rec      = (int2*)take((size_t)2 * E * 8);

    const bool bucket_ok = (nb2 <= 1024) && (nblk <= 1024) && (N < (1 << 23)) &&
                           (off <= ws_size);

    const int eb = (E + THREADS - 1) / THREADS;
    const int nb = (N + THREADS - 1) / THREADS;

    if (bucket_ok) {
        // dynamic LDS for scatter (must match device-side layout)
        size_t scat_lds = (size_t)(4 * SEG) * 4      // skey+sval int[2*SEG] each
                        + (size_t)(3 * nb2) * 4      // cur/sbase/scur
                        + 256 * 4                    // stmp
                        + (size_t)(2 * SEG) * 2;     // bid ushort

        hist_kernel<<<SB, THREADS, nb2 * 4, stream>>>(row, col, TU, E, NB, chunk);
        scan1_kernel<<<nblk, 256, 0, stream>>>(TU, bsum, n2);
        scan2_kernel<<<1, 1024, 0, stream>>>(bsum, boff, nblk);
        scan3_kernel<<<(n2 + 256) / 256, 256, 0, stream>>>(TU, boff, n2, nblk);
        scatter_kernel<<<SB, THREADS, scat_lds, stream>>>(row, col, ew, TU, rec, E, NB, chunk);
        degred_kernel<<<NB * DM, THREADS, 0, stream>>>(rec, TU, pdeg);
        init_kernel<<<nb, THREADS, 0, stream>>>(x, pdeg, dis, A, outacc, Wc, N);
        // node-level sort + norm bake; sorted records land in the row half of rec
        nodesort_kernel<<<NB, 1024, 0, stream>>>(rec, TU, dis, rec, rowstart, NB, N);

        const int gb = (N + (THREADS / 16) - 1) / (THREADS / 16);
        // k = 1..K-1, Chebyshev update fused into gather epilogue
        gather_kernel<<<gb, THREADS, 0, stream>>>(rec, rowstart, A, (const float2*)nullptr,
                                                  B, outacc, Wc, 1, N);
        float2 *t0 = A, *t1 = B, *fr = C;
        for (int k = 2; k < K; ++k) {
            gather_kernel<<<gb, THREADS, 0, stream>>>(rec, rowstart, t1, t0, fr, outacc, Wc, k, N);
            float2* n0 = t1; float2* n1 = fr; float2* nf = t0;
            t0 = n0; t1 = n1; fr = nf;
        }
    } else {
        // ---- full-atomic fallback ----
        zero_kernel<<<nb, THREADS, 0, stream>>>(dis, N);
        deg_at_kernel<<<eb, THREADS, 0, stream>>>(row, col, ew, dis, E);
        init_at_kernel<<<nb, THREADS, 0, stream>>>(x, dis, A, outacc, Wc, N);
        zerof2_kernel<<<nb, THREADS, 0, stream>>>(B, N);
        prop_kernel<<<eb, THREADS, 0, stream>>>(row, col, ew, dis, A, B, E);
        cheb_at_kernel<<<nb, THREADS, 0, stream>>>(B, (const float2*)nullptr, outacc, Wc, 1, N);
        float2 *t0 = A, *t1 = B, *fr = C;
        for (int k = 2; k < K; ++k) {
            zerof2_kernel<<<nb, THREADS, 0, stream>>>(fr, N);
            prop_kernel<<<eb, THREADS, 0, stream>>>(row, col, ew, dis, t1, fr, E);
            cheb_at_kernel<<<nb, THREADS, 0, stream>>>(fr, t0, outacc, Wc, k, N);
            float2* n0 = t1; float2* n1 = fr; float2* nf = t0;
            t0 = n0; t1 = n1; fr = nf;
        }
    }

    u_ms_kernel<<<nb, THREADS, 0, stream>>>(x, outacc, cb, W, b, U, part, N);
    red_ms_kernel<<<1, 1024, 0, stream>>>(part, nb, scal);
    out_kernel<<<nb, THREADS, 0, stream>>>(U, scal, out, N);
}

// Round 14
// 412.874 us; speedup vs baseline: 1.1097x; 1.1097x over previous
//
#include <hip/hip_runtime.h>
#include <math.h>

#define THREADS 256
#define SB 1024           // blocks for hist/scatter passes (chunked edge ranges)
#define BSH 8             // bucket shift: 256 nodes per bucket
#define BSZ 256
#define BMSK 255
#define SEG 2048          // edges per scatter segment (8 per thread)
#define DM 8              // degred split factor

typedef int int4n __attribute__((ext_vector_type(4)));   // native vector for nontemporal builtins

// ---------------------------------------------------------------------------
// Per-block LDS histograms over node buckets (bucket = 256 nodes).
__global__ void hist_kernel(const int* __restrict__ row, const int* __restrict__ col,
                            int* __restrict__ TU, int E, int NB, int chunk) {
    extern __shared__ int sh[];
    int t = threadIdx.x, b = blockIdx.x;
    for (int k = t; k < 2 * NB; k += THREADS) sh[k] = 0;
    __syncthreads();
    int lo = b * chunk;
    int hi = min(lo + chunk, E);
    for (int e = lo + t; e < hi; e += THREADS) {
        int r = row[e], c = col[e];
        if (r != c) {
            atomicAdd(&sh[r >> BSH], 1);
            atomicAdd(&sh[NB + (c >> BSH)], 1);
        }
    }
    __syncthreads();
    for (int k = t; k < 2 * NB; k += THREADS) TU[k * SB + b] = sh[k];
}

// ---------------------------------------------------------------------------
// Exclusive scan, 1024 entries per block (4 serial per thread + block scan).
__global__ void scan1_kernel(int* __restrict__ data, int* __restrict__ bsum, int n) {
    __shared__ int s[256];
    int t = threadIdx.x;
    int base = blockIdx.x * 1024 + t * 4;
    int a0 = (base + 0 < n) ? data[base + 0] : 0;
    int a1 = (base + 1 < n) ? data[base + 1] : 0;
    int a2 = (base + 2 < n) ? data[base + 2] : 0;
    int a3 = (base + 3 < n) ? data[base + 3] : 0;
    int tsum = a0 + a1 + a2 + a3;
    s[t] = tsum;
    __syncthreads();
    for (int d = 1; d < 256; d <<= 1) {
        int xv = (t >= d) ? s[t - d] : 0;
        __syncthreads();
        s[t] += xv;
        __syncthreads();
    }
    int excl = s[t] - tsum;
    if (base + 0 < n) data[base + 0] = excl;
    if (base + 1 < n) data[base + 1] = excl + a0;
    if (base + 2 < n) data[base + 2] = excl + a0 + a1;
    if (base + 3 < n) data[base + 3] = excl + a0 + a1 + a2;
    if (t == 255) bsum[blockIdx.x] = s[255];
}

__global__ void scan2_kernel(const int* __restrict__ bsum, int* __restrict__ boff, int nb) {
    __shared__ int s[1024];
    int t = threadIdx.x;
    int v = (t < nb) ? bsum[t] : 0;
    s[t] = v;
    __syncthreads();
    for (int d = 1; d < 1024; d <<= 1) {
        int xv = (t >= d) ? s[t - d] : 0;
        __syncthreads();
        s[t] += xv;
        __syncthreads();
    }
    if (t < nb) boff[t] = s[t] - v;
    if (t == nb - 1) boff[nb] = s[t];            // grand total
}

__global__ void scan3_kernel(int* __restrict__ data, const int* __restrict__ boff,
                             int n, int nbk) {
    int i = blockIdx.x * blockDim.x + threadIdx.x;
    if (i < n) data[i] += boff[i >> 10];
    else if (i == n) data[n] = boff[nbk];        // append grand total
}

// ---------------------------------------------------------------------------
// Scatter with segment-local counting sort: SEG=2048 (long per-bucket runs,
// ~32 records = 4 full lines) + SoA LDS staging (4B writes, ~2-way aliasing).
__global__ void scatter_kernel(const int* __restrict__ row, const int* __restrict__ col,
                               const float* __restrict__ ew,
                               const int* __restrict__ TU, int2* __restrict__ rec,
                               int E, int NB, int chunk) {
    extern __shared__ int shl[];
    const int nb2 = 2 * NB;                                    // <= 1024
    int* skey  = shl;                                          // [2*SEG]
    int* sval  = skey + 2 * SEG;                               // [2*SEG]
    int* cur   = sval + 2 * SEG;                               // [nb2]
    int* sbase = cur + nb2;                                    // [nb2]
    int* scur  = sbase + nb2;                                  // [nb2]
    int* stmp  = scur + nb2;                                   // [256]
    unsigned short* bid = (unsigned short*)(stmp + 256);       // [2*SEG]

    int t = threadIdx.x, b = blockIdx.x;
    for (int k = t; k < nb2; k += THREADS) cur[k] = TU[k * SB + b];
    int lo = b * chunk;
    int hi = min(lo + chunk, E);

    for (int slo = lo; slo < hi; slo += SEG) {
        int scount = min(SEG, hi - slo);
        for (int k = t; k < nb2; k += THREADS) sbase[k] = 0;
        __syncthreads();

        int er[8], ec[8];
        float ewv[8];
#pragma unroll
        for (int j = 0; j < 8; ++j) {
            er[j] = -1;
            int e = slo + j * THREADS + t;
            if (e < slo + scount) {
                int r = row[e], c = col[e];
                if (r != c) {
                    er[j] = r; ec[j] = c; ewv[j] = ew[e];
                    atomicAdd(&sbase[r >> BSH], 1);
                    atomicAdd(&sbase[NB + (c >> BSH)], 1);
                }
            }
        }
        __syncthreads();

        // exclusive scan of nb2 per-bucket counts (4 serial + 256 block scan)
        int b4 = t * 4;
        int a0 = (b4 + 0 < nb2) ? sbase[b4 + 0] : 0;
        int a1 = (b4 + 1 < nb2) ? sbase[b4 + 1] : 0;
        int a2 = (b4 + 2 < nb2) ? sbase[b4 + 2] : 0;
        int a3 = (b4 + 3 < nb2) ? sbase[b4 + 3] : 0;
        int tsum = a0 + a1 + a2 + a3;
        stmp[t] = tsum;
        __syncthreads();
        for (int d = 1; d < 256; d <<= 1) {
            int xv = (t >= d) ? stmp[t - d] : 0;
            __syncthreads();
            stmp[t] += xv;
            __syncthreads();
        }
        int excl = stmp[t] - tsum;
        int total = stmp[255];
        __syncthreads();
        if (b4 + 0 < nb2) { sbase[b4 + 0] = excl;                scur[b4 + 0] = excl; }
        if (b4 + 1 < nb2) { sbase[b4 + 1] = excl + a0;           scur[b4 + 1] = excl + a0; }
        if (b4 + 2 < nb2) { sbase[b4 + 2] = excl + a0 + a1;      scur[b4 + 2] = excl + a0 + a1; }
        if (b4 + 3 < nb2) { sbase[b4 + 3] = excl + a0 + a1 + a2; scur[b4 + 3] = excl + a0 + a1 + a2; }
        __syncthreads();

        // ranked placement into bucket-ordered SoA staging
#pragma unroll
        for (int j = 0; j < 8; ++j) {
            if (er[j] >= 0) {
                int r = er[j], c = ec[j];
                int wbits = __float_as_int(ewv[j]);
                int k1 = r >> BSH;
                int p1 = atomicAdd(&scur[k1], 1);
                skey[p1] = r & BMSK;
                sval[p1] = wbits;
                bid[p1] = (unsigned short)k1;
                int k2 = NB + (c >> BSH);
                int p2 = atomicAdd(&scur[k2], 1);
                skey[p2] = (r << BSH) | (c & BMSK);
                sval[p2] = wbits;
                bid[p2] = (unsigned short)k2;
            }
        }
        __syncthreads();

        // cooperative dense write-out (consecutive lanes -> consecutive addrs)
        for (int j = t; j < total; j += THREADS) {
            int k = bid[j];
            rec[cur[k] + (j - sbase[k])] = make_int2(skey[j], sval[j]);
        }
        __syncthreads();

        for (int k = t; k < nb2; k += THREADS) cur[k] += scur[k] - sbase[k];
        __syncthreads();
    }
}

// ---------------------------------------------------------------------------
// deg partials over ROW half: grid = NB*DM, 256-slot LDS acc, plain writes.
__global__ void degred_kernel(const int2* __restrict__ rec, const int* __restrict__ TU,
                              float* __restrict__ pdeg) {
    __shared__ float acc[BSZ];
    int t = threadIdx.x;
    int bk = blockIdx.x / DM, m = blockIdx.x % DM;
    acc[t] = 0.f;
    __syncthreads();
    int s = TU[bk * SB];
    int e2 = TU[(bk + 1) * SB];
    int len = e2 - s;
    int lo = s + (int)((long long)len * m / DM);
    int hi = s + (int)((long long)len * (m + 1) / DM);
    int i = lo + t;
    for (; i + 3 * THREADS < hi; i += 4 * THREADS) {
        int2 p0 = rec[i];
        int2 p1 = rec[i + THREADS];
        int2 p2 = rec[i + 2 * THREADS];
        int2 p3 = rec[i + 3 * THREADS];
        atomicAdd(&acc[p0.x], __int_as_float(p0.y));
        atomicAdd(&acc[p1.x], __int_as_float(p1.y));
        atomicAdd(&acc[p2.x], __int_as_float(p2.y));
        atomicAdd(&acc[p3.x], __int_as_float(p3.y));
    }
    for (; i < hi; i += THREADS) {
        int2 p = rec[i];
        atomicAdd(&acc[p.x], __int_as_float(p.y));
    }
    __syncthreads();
    pdeg[(size_t)(bk * DM + m) * BSZ + t] = acc[t];
}

// ---------------------------------------------------------------------------
// init (fused deg-partial reduce): dis = rsqrt(sum pdeg); Tx0 = x[:, :2];
// outacc = Tx0 @ Wc[0].
__global__ void init_kernel(const float* __restrict__ x, const float* __restrict__ pdeg,
                            float* __restrict__ dis, float2* __restrict__ tx0,
                            float2* __restrict__ outacc, const float* __restrict__ Wc,
                            int N) {
    int i = blockIdx.x * blockDim.x + threadIdx.x;
    if (i >= N) return;
    int bk = i >> BSH, li = i & BMSK;
    const float* src = pdeg + (size_t)bk * DM * BSZ + li;
    float d = 0.f;
    for (int m = 0; m < DM; ++m) d += src[(size_t)m * BSZ];
    dis[i] = (d > 0.f) ? rsqrtf(d) : 0.f;
    float x0 = x[3 * i + 0];
    float x1 = x[3 * i + 1];
    tx0[i] = make_float2(x0, x1);
    outacc[i] = make_float2(x0 * Wc[0] + x1 * Wc[2],
                            x0 * Wc[1] + x1 * Wc[3]);
}

// ---------------------------------------------------------------------------
// Node-level sort of the COL half + norm baking -> per-node CSR.
// One 1024-thread block per col bucket; sorted {r_global, norm} records land
// in the row-half region of rec (dead after degred).
__global__ void nodesort_kernel(const int2* __restrict__ rec, const int* __restrict__ TU,
                                const float* __restrict__ dis,
                                int2* __restrict__ srec, int* __restrict__ rowstart,
                                int NB, int N) {
    __shared__ int cnt[BSZ], cur[BSZ], stmp[BSZ];
    __shared__ float disc[BSZ];
    int t = threadIdx.x, bk = blockIdx.x;
    int colbase = TU[NB * SB];
    if (t < BSZ) {
        cnt[t] = 0;
        int node = (bk << BSH) + t;
        disc[t] = (node < N) ? dis[node] : 0.f;
    }
    __syncthreads();
    int s = TU[(NB + bk) * SB];
    int e = TU[(NB + bk + 1) * SB];
    for (int i = s + t; i < e; i += 1024) atomicAdd(&cnt[rec[i].x & BMSK], 1);
    __syncthreads();
    if (t < BSZ) stmp[t] = cnt[t];
    __syncthreads();
    for (int d = 1; d < BSZ; d <<= 1) {
        int xv = (t >= d && t < BSZ) ? stmp[t - d] : 0;
        __syncthreads();
        if (t < BSZ) stmp[t] += xv;
        __syncthreads();
    }
    if (t < BSZ) {
        int g = (s - colbase) + stmp[t] - cnt[t];
        cur[t] = g;
        rowstart[(bk << BSH) + t] = g;
        if (bk == NB - 1 && t == 0) rowstart[NB << BSH] = e - colbase;
    }
    __syncthreads();
    for (int i = s + t; i < e; i += 1024) {
        int2 p = rec[i];
        int cl = p.x & BMSK;
        int r = ((unsigned)p.x) >> BSH;
        float w = -dis[r] * __int_as_float(p.y) * disc[cl];
        int pos = atomicAdd(&cur[cl], 1);
        srec[pos] = make_int2(r, __float_as_int(w));
    }
}

// ---------------------------------------------------------------------------
// Propagation with fused Chebyshev update: 16 lanes per node, paired 16B
// nontemporal record loads (2 records / lane), dual accumulators, w16 reduce.
__global__ void gather_kernel(const int2* __restrict__ srec, const int* __restrict__ rowstart,
                              const float2* __restrict__ h, const float2* __restrict__ tx0,
                              float2* __restrict__ vout, float2* __restrict__ outacc,
                              const float* __restrict__ Wc, int k, int N) {
    int g = blockIdx.x * (THREADS / 16) + (threadIdx.x >> 4);
    int lane = threadIdx.x & 15;
    if (g >= N) return;
    int s = rowstart[g];
    int e = rowstart[g + 1];
    float sx0 = 0.f, sy0 = 0.f, sx1 = 0.f, sy1 = 0.f;
    int a = (s + 1) & ~1;                        // first even index >= s
    if ((s & 1) && lane == 15 && s < e) {        // odd head record
        int2 p = srec[s];
        float2 hv = h[p.x];
        float w = __int_as_float(p.y);
        sx0 = fmaf(w, hv.x, sx0); sy0 = fmaf(w, hv.y, sy0);
    }
    for (int i = a + 2 * lane; i < e; i += 32) {
        if (i + 1 < e) {
            int4n v = __builtin_nontemporal_load((const int4n*)(srec + i));
            float w0 = __int_as_float(v.y);
            float w1 = __int_as_float(v.w);
            float2 h0 = h[v.x];
            float2 h1 = h[v.z];
            sx0 = fmaf(w0, h0.x, sx0); sy0 = fmaf(w0, h0.y, sy0);
            sx1 = fmaf(w1, h1.x, sx1); sy1 = fmaf(w1, h1.y, sy1);
        } else {
            int2 p = srec[i];
            float2 hv = h[p.x];
            float w = __int_as_float(p.y);
            sx0 = fmaf(w, hv.x, sx0); sy0 = fmaf(w, hv.y, sy0);
        }
    }
    float sx = sx0 + sx1, sy = sy0 + sy1;
    for (int off = 8; off > 0; off >>= 1) {
        sx += __shfl_down(sx, off, 16);
        sy += __shfl_down(sy, off, 16);
    }
    if (lane == 0) {
        float2 v = make_float2(sx, sy);
        if (tx0) {
            float2 tv = tx0[g];
            v.x = 2.f * v.x - tv.x;
            v.y = 2.f * v.y - tv.y;
        }
        vout[g] = v;
        float2 o = outacc[g];
        o.x += v.x * Wc[4 * k + 0] + v.y * Wc[4 * k + 2];
        o.y += v.x * Wc[4 * k + 1] + v.y * Wc[4 * k + 3];
        outacc[g] = o;
    }
}

// ---------------------------------------------------------------------------
// Full-atomic fallback kernels (only if workspace is too small).
__global__ void zero_kernel(float* __restrict__ p, int n) {
    int i = blockIdx.x * blockDim.x + threadIdx.x;
    if (i < n) p[i] = 0.f;
}
__global__ void zerof2_kernel(float2* __restrict__ p, int n) {
    int i = blockIdx.x * blockDim.x + threadIdx.x;
    if (i < n) p[i] = make_float2(0.f, 0.f);
}
__global__ void deg_at_kernel(const int* __restrict__ row, const int* __restrict__ col,
                              const float* __restrict__ ew, float* __restrict__ deg, int E) {
    int e = blockIdx.x * blockDim.x + threadIdx.x;
    if (e >= E) return;
    int r = row[e], c = col[e];
    if (r != c) atomicAdd(&deg[r], ew[e]);
}
__global__ void init_at_kernel(const float* __restrict__ x, float* __restrict__ deg,
                               float2* __restrict__ tx0, float2* __restrict__ outacc,
                               const float* __restrict__ Wc, int N) {
    int i = blockIdx.x * blockDim.x + threadIdx.x;
    if (i >= N) return;
    float d = deg[i];
    deg[i] = (d > 0.f) ? rsqrtf(d) : 0.f;
    float x0 = x[3 * i + 0];
    float x1 = x[3 * i + 1];
    tx0[i] = make_float2(x0, x1);
    outacc[i] = make_float2(x0 * Wc[0] + x1 * Wc[2],
                            x0 * Wc[1] + x1 * Wc[3]);
}
__global__ void prop_kernel(const int* __restrict__ row, const int* __restrict__ col,
                            const float* __restrict__ ew, const float* __restrict__ dis,
                            const float2* __restrict__ h, float2* __restrict__ o, int E) {
    int e = blockIdx.x * blockDim.x + threadIdx.x;
    if (e >= E) return;
    int r = row[e], c = col[e];
    if (r == c) return;
    float w = -dis[r] * ew[e] * dis[c];
    if (w == 0.f) return;
    float2 hv = h[r];
    atomicAdd(&o[c].x, w * hv.x);
    atomicAdd(&o[c].y, w * hv.y);
}
__global__ void cheb_at_kernel(float2* __restrict__ raw, const float2* __restrict__ tx0,
                               float2* __restrict__ outacc, const float* __restrict__ Wc,
                               int k, int N) {
    int i = blockIdx.x * blockDim.x + threadIdx.x;
    if (i >= N) return;
    float2 v = raw[i];
    if (tx0) {
        float2 t = tx0[i];
        v.x = 2.f * v.x - t.x;
        v.y = 2.f * v.y - t.y;
        raw[i] = v;
    }
    float2 o = outacc[i];
    o.x += v.x * Wc[4 * k + 0] + v.y * Wc[4 * k + 2];
    o.y += v.x * Wc[4 * k + 1] + v.y * Wc[4 * k + 3];
    outacc[i] = o;
}

// ---------------------------------------------------------------------------
// Fused epilogue (3 kernels): per-block (max, sum-of-exp) via LSE rescale.
__global__ void u_ms_kernel(const float* __restrict__ x, const float2* __restrict__ outacc,
                            const float* __restrict__ cb, const float* __restrict__ W,
                            const float* __restrict__ b, float* __restrict__ U,
                            float* __restrict__ part2, int N) {
    __shared__ float sm[THREADS / 64];
    __shared__ float bmax;
    int i = blockIdx.x * blockDim.x + threadIdx.x;
    int t = threadIdx.x;
    float u = -INFINITY;
    if (i < N) {
        float2 o = outacc[i];
        float h0 = fmaxf(o.x + cb[0], 0.f);
        float h1 = fmaxf(o.y + cb[1], 0.f);
        u = x[3 * i + 2] * W[0] + h0 * W[1] + h1 * W[2] + b[0];
        U[i] = u;
    }
    float mv = u;
    for (int off = 32; off > 0; off >>= 1) mv = fmaxf(mv, __shfl_down(mv, off));
    if ((t & 63) == 0) sm[t >> 6] = mv;
    __syncthreads();
    if (t == 0) {
        float m = sm[0];
        for (int w = 1; w < THREADS / 64; ++w) m = fmaxf(m, sm[w]);
        bmax = m;
    }
    __syncthreads();
    float bm = bmax;
    float e = (i < N) ? expf(u - bm) : 0.f;
    for (int off = 32; off > 0; off >>= 1) e += __shfl_down(e, off);
    __syncthreads();
    if ((t & 63) == 0) sm[t >> 6] = e;
    __syncthreads();
    if (t == 0) {
        float s = sm[0];
        for (int w = 1; w < THREADS / 64; ++w) s += sm[w];
        part2[2 * blockIdx.x]     = bm;
        part2[2 * blockIdx.x + 1] = s;
    }
}

__global__ void red_ms_kernel(const float* __restrict__ part2, int n,
                              float* __restrict__ scal) {
    __shared__ float sm[16];
    __shared__ float gmax;
    int t = threadIdx.x;
    float m = -INFINITY;
    for (int i = t; i < n; i += blockDim.x) m = fmaxf(m, part2[2 * i]);
    for (int off = 32; off > 0; off >>= 1) m = fmaxf(m, __shfl_down(m, off));
    int wid = t >> 6;
    if ((t & 63) == 0) sm[wid] = m;
    __syncthreads();
    if (t == 0) {
        float r = sm[0];
        int nw = blockDim.x >> 6;
        for (int w = 1; w < nw; ++w) r = fmaxf(r, sm[w]);
        gmax = r;
    }
    __syncthreads();
    float M = gmax;
    float s = 0.f;
    for (int i = t; i < n; i += blockDim.x) s += part2[2 * i + 1] * expf(part2[2 * i] - M);
    for (int off = 32; off > 0; off >>= 1) s += __shfl_down(s, off);
    __syncthreads();
    if ((t & 63) == 0) sm[wid] = s;
    __syncthreads();
    if (t == 0) {
        float r = sm[0];
        int nw = blockDim.x >> 6;
        for (int w = 1; w < nw; ++w) r += sm[w];
        scal[0] = M;
        scal[1] = 1.f / r;
    }
}

__global__ void out_kernel(const float* __restrict__ U, const float* __restrict__ scal,
                           float* __restrict__ out, int N) {
    int i = blockIdx.x * blockDim.x + threadIdx.x;
    if (i < N) out[i] = expf(U[i] - scal[0]) * scal[1];
}

// ---------------------------------------------------------------------------
extern "C" void kernel_launch(void* const* d_in, const int* in_sizes, int n_in,
                              void* d_out, int out_size, void* d_ws, size_t ws_size,
                              hipStream_t stream) {
    (void)n_in; (void)out_size;
    const float* x    = (const float*)d_in[0];
    const int*   eidx = (const int*)d_in[1];     // int32 per harness contract
    const float* ew   = (const float*)d_in[2];
    const float* Wc   = (const float*)d_in[3];
    const float* cb   = (const float*)d_in[4];
    const float* W    = (const float*)d_in[5];
    const float* b    = (const float*)d_in[6];
    float*       out  = (float*)d_out;

    const int N = in_sizes[0] / 3;
    const int E = in_sizes[2];
    const int K = in_sizes[3] / 4;
    const int* row = eidx;
    const int* col = eidx + E;

    const int NB    = (N + BMSK) >> BSH;         // 256-node buckets
    const int nb2   = 2 * NB;
    const int n2    = nb2 * SB;                  // unified count-table length
    const int nblk  = (n2 + 1023) / 1024;        // scan1 blocks (1024/block)
    const int chunk = (E + SB - 1) / SB;
    const int Npad  = NB << BSH;

    char* ws = (char*)d_ws;
    size_t off = 0;
    auto take = [&](size_t bytes) -> void* {
        void* p = ws + off;
        off = (off + bytes + 255) & ~(size_t)255;
        return p;
    };

    float*  dis      = (float*)take((size_t)N * 4);
    float2* A        = (float2*)take((size_t)N * 8);
    float2* B        = (float2*)take((size_t)N * 8);
    float2* C        = (float2*)take((size_t)N * 8);
    float2* outacc   = (float2*)take((size_t)N * 8);
    float*  U        = (float*)take((size_t)N * 4);
    float*  part     = (float*)take(8192 * 4);
    float*  scal     = (float*)take(64 * 4);
    int*    TU       = (int*)take((size_t)(n2 + 1) * 4);
    int*    bsum     = (int*)take(1024 * 4);
    int*    boff     = (int*)take(1025 * 4);
    int*    rowstart = (int*)take((size_t)(Npad + 1) * 4);
    float*  pdeg     = (float*)take((size_t)NB * DM * BSZ * 4);
    int2*   rec      = (int2*)take((size_t)2 * E * 8);

    const bool bucket_ok = (nb2 <= 1024) && (nblk <= 1024) && (N < (1 << 23)) &&
                           (off <= ws_size);

    const int eb = (E + THREADS - 1) / THREADS;
    const int nb = (N + THREADS - 1) / THREADS;

    if (bucket_ok) {
        // dynamic LDS for scatter (must match device-side layout)
        size_t scat_lds = (size_t)(4 * SEG) * 4      // skey+sval int[2*SEG] each
                        + (size_t)(3 * nb2) * 4      // cur/sbase/scur
                        + 256 * 4                    // stmp
                        + (size_t)(2 * SEG) * 2;     // bid ushort

        hist_kernel<<<SB, THREADS, nb2 * 4, stream>>>(row, col, TU, E, NB, chunk);
        scan1_kernel<<<nblk, 256, 0, stream>>>(TU, bsum, n2);
        scan2_kernel<<<1, 1024, 0, stream>>>(bsum, boff, nblk);
        scan3_kernel<<<(n2 + 256) / 256, 256, 0, stream>>>(TU, boff, n2, nblk);
        scatter_kernel<<<SB, THREADS, scat_lds, stream>>>(row, col, ew, TU, rec, E, NB, chunk);
        degred_kernel<<<NB * DM, THREADS, 0, stream>>>(rec, TU, pdeg);
        init_kernel<<<nb, THREADS, 0, stream>>>(x, pdeg, dis, A, outacc, Wc, N);
        // node-level sort + norm bake; sorted records land in the row half of rec
        nodesort_kernel<<<NB, 1024, 0, stream>>>(rec, TU, dis, rec, rowstart, NB, N);

        const int gb = (N + (THREADS / 16) - 1) / (THREADS / 16);
        // k = 1..K-1, Chebyshev update fused into gather epilogue
        gather_kernel<<<gb, THREADS, 0, stream>>>(rec, rowstart, A, (const float2*)nullptr,
                                                  B, outacc, Wc, 1, N);
        float2 *t0 = A, *t1 = B, *fr = C;
        for (int k = 2; k < K; ++k) {
            gather_kernel<<<gb, THREADS, 0, stream>>>(rec, rowstart, t1, t0, fr, outacc, Wc, k, N);
            float2* n0 = t1; float2* n1 = fr; float2* nf = t0;
            t0 = n0; t1 = n1; fr = nf;
        }
    } else {
        // ---- full-atomic fallback ----
        zero_kernel<<<nb, THREADS, 0, stream>>>(dis, N);
        deg_at_kernel<<<eb, THREADS, 0, stream>>>(row, col, ew, dis, E);
        init_at_kernel<<<nb, THREADS, 0, stream>>>(x, dis, A, outacc, Wc, N);
        zerof2_kernel<<<nb, THREADS, 0, stream>>>(B, N);
        prop_kernel<<<eb, THREADS, 0, stream>>>(row, col, ew, dis, A, B, E);
        cheb_at_kernel<<<nb, THREADS, 0, stream>>>(B, (const float2*)nullptr, outacc, Wc, 1, N);
        float2 *t0 = A, *t1 = B, *fr = C;
        for (int k = 2; k < K; ++k) {
            zerof2_kernel<<<nb, THREADS, 0, stream>>>(fr, N);
            prop_kernel<<<eb, THREADS, 0, stream>>>(row, col, ew, dis, t1, fr, E);
            cheb_at_kernel<<<nb, THREADS, 0, stream>>>(fr, t0, outacc, Wc, k, N);
            float2* n0 = t1; float2* n1 = fr; float2* nf = t0;
            t0 = n0; t1 = n1; fr = nf;
        }
    }

    u_ms_kernel<<<nb, THREADS, 0, stream>>>(x, outacc, cb, W, b, U, part, N);
    red_ms_kernel<<<1, 1024, 0, stream>>>(part, nb, scal);
    out_kernel<<<nb, THREADS, 0, stream>>>(U, scal, out, N);
}

// Round 15
// 412.019 us; speedup vs baseline: 1.1120x; 1.0021x over previous
//
#include <hip/hip_runtime.h>
#include <math.h>

#define THREADS 256
#define SB 1024           // blocks for hist/scatter passes (chunked edge ranges)
#define BSH 8             // bucket shift: 256 nodes per bucket
#define BSZ 256
#define BMSK 255
#define SEG 2048          // edges per scatter segment (8 per thread)
#define DM 8              // degred split factor

typedef int int4n __attribute__((ext_vector_type(4)));   // native vector for nontemporal builtins

// ---------------------------------------------------------------------------
// Per-block LDS histograms over node buckets (bucket = 256 nodes).
__global__ void hist_kernel(const int* __restrict__ row, const int* __restrict__ col,
                            int* __restrict__ TU, int E, int NB, int chunk) {
    extern __shared__ int sh[];
    int t = threadIdx.x, b = blockIdx.x;
    for (int k = t; k < 2 * NB; k += THREADS) sh[k] = 0;
    __syncthreads();
    int lo = b * chunk;
    int hi = min(lo + chunk, E);
    for (int e = lo + t; e < hi; e += THREADS) {
        int r = row[e], c = col[e];
        if (r != c) {
            atomicAdd(&sh[r >> BSH], 1);
            atomicAdd(&sh[NB + (c >> BSH)], 1);
        }
    }
    __syncthreads();
    for (int k = t; k < 2 * NB; k += THREADS) TU[k * SB + b] = sh[k];
}

// ---------------------------------------------------------------------------
// Exclusive scan, 1024 entries per block (4 serial per thread + block scan).
__global__ void scan1_kernel(int* __restrict__ data, int* __restrict__ bsum, int n) {
    __shared__ int s[256];
    int t = threadIdx.x;
    int base = blockIdx.x * 1024 + t * 4;
    int a0 = (base + 0 < n) ? data[base + 0] : 0;
    int a1 = (base + 1 < n) ? data[base + 1] : 0;
    int a2 = (base + 2 < n) ? data[base + 2] : 0;
    int a3 = (base + 3 < n) ? data[base + 3] : 0;
    int tsum = a0 + a1 + a2 + a3;
    s[t] = tsum;
    __syncthreads();
    for (int d = 1; d < 256; d <<= 1) {
        int xv = (t >= d) ? s[t - d] : 0;
        __syncthreads();
        s[t] += xv;
        __syncthreads();
    }
    int excl = s[t] - tsum;
    if (base + 0 < n) data[base + 0] = excl;
    if (base + 1 < n) data[base + 1] = excl + a0;
    if (base + 2 < n) data[base + 2] = excl + a0 + a1;
    if (base + 3 < n) data[base + 3] = excl + a0 + a1 + a2;
    if (t == 255) bsum[blockIdx.x] = s[255];
}

__global__ void scan2_kernel(const int* __restrict__ bsum, int* __restrict__ boff, int nb) {
    __shared__ int s[1024];
    int t = threadIdx.x;
    int v = (t < nb) ? bsum[t] : 0;
    s[t] = v;
    __syncthreads();
    for (int d = 1; d < 1024; d <<= 1) {
        int xv = (t >= d) ? s[t - d] : 0;
        __syncthreads();
        s[t] += xv;
        __syncthreads();
    }
    if (t < nb) boff[t] = s[t] - v;
    if (t == nb - 1) boff[nb] = s[t];            // grand total
}

__global__ void scan3_kernel(int* __restrict__ data, const int* __restrict__ boff,
                             int n, int nbk) {
    int i = blockIdx.x * blockDim.x + threadIdx.x;
    if (i < n) data[i] += boff[i >> 10];
    else if (i == n) data[n] = boff[nbk];        // append grand total
}

// ---------------------------------------------------------------------------
// Scatter with segment-local counting sort: SEG=2048 (long per-bucket runs,
// ~32 records = 4 full lines) + SoA LDS staging (4B writes, ~2-way aliasing).
__global__ void scatter_kernel(const int* __restrict__ row, const int* __restrict__ col,
                               const float* __restrict__ ew,
                               const int* __restrict__ TU, int2* __restrict__ rec,
                               int E, int NB, int chunk) {
    extern __shared__ int shl[];
    const int nb2 = 2 * NB;                                    // <= 1024
    int* skey  = shl;                                          // [2*SEG]
    int* sval  = skey + 2 * SEG;                               // [2*SEG]
    int* cur   = sval + 2 * SEG;                               // [nb2]
    int* sbase = cur + nb2;                                    // [nb2]
    int* scur  = sbase + nb2;                                  // [nb2]
    int* stmp  = scur + nb2;                                   // [256]
    unsigned short* bid = (unsigned short*)(stmp + 256);       // [2*SEG]

    int t = threadIdx.x, b = blockIdx.x;
    for (int k = t; k < nb2; k += THREADS) cur[k] = TU[k * SB + b];
    int lo = b * chunk;
    int hi = min(lo + chunk, E);

    for (int slo = lo; slo < hi; slo += SEG) {
        int scount = min(SEG, hi - slo);
        for (int k = t; k < nb2; k += THREADS) sbase[k] = 0;
        __syncthreads();

        int er[8], ec[8];
        float ewv[8];
#pragma unroll
        for (int j = 0; j < 8; ++j) {
            er[j] = -1;
            int e = slo + j * THREADS + t;
            if (e < slo + scount) {
                int r = row[e], c = col[e];
                if (r != c) {
                    er[j] = r; ec[j] = c; ewv[j] = ew[e];
                    atomicAdd(&sbase[r >> BSH], 1);
                    atomicAdd(&sbase[NB + (c >> BSH)], 1);
                }
            }
        }
        __syncthreads();

        // exclusive scan of nb2 per-bucket counts (4 serial + 256 block scan)
        int b4 = t * 4;
        int a0 = (b4 + 0 < nb2) ? sbase[b4 + 0] : 0;
        int a1 = (b4 + 1 < nb2) ? sbase[b4 + 1] : 0;
        int a2 = (b4 + 2 < nb2) ? sbase[b4 + 2] : 0;
        int a3 = (b4 + 3 < nb2) ? sbase[b4 + 3] : 0;
        int tsum = a0 + a1 + a2 + a3;
        stmp[t] = tsum;
        __syncthreads();
        for (int d = 1; d < 256; d <<= 1) {
            int xv = (t >= d) ? stmp[t - d] : 0;
            __syncthreads();
            stmp[t] += xv;
            __syncthreads();
        }
        int excl = stmp[t] - tsum;
        int total = stmp[255];
        __syncthreads();
        if (b4 + 0 < nb2) { sbase[b4 + 0] = excl;                scur[b4 + 0] = excl; }
        if (b4 + 1 < nb2) { sbase[b4 + 1] = excl + a0;           scur[b4 + 1] = excl + a0; }
        if (b4 + 2 < nb2) { sbase[b4 + 2] = excl + a0 + a1;      scur[b4 + 2] = excl + a0 + a1; }
        if (b4 + 3 < nb2) { sbase[b4 + 3] = excl + a0 + a1 + a2; scur[b4 + 3] = excl + a0 + a1 + a2; }
        __syncthreads();

        // ranked placement into bucket-ordered SoA staging
#pragma unroll
        for (int j = 0; j < 8; ++j) {
            if (er[j] >= 0) {
                int r = er[j], c = ec[j];
                int wbits = __float_as_int(ewv[j]);
                int k1 = r >> BSH;
                int p1 = atomicAdd(&scur[k1], 1);
                skey[p1] = r & BMSK;
                sval[p1] = wbits;
                bid[p1] = (unsigned short)k1;
                int k2 = NB + (c >> BSH);
                int p2 = atomicAdd(&scur[k2], 1);
                skey[p2] = (r << BSH) | (c & BMSK);
                sval[p2] = wbits;
                bid[p2] = (unsigned short)k2;
            }
        }
        __syncthreads();

        // cooperative dense write-out (consecutive lanes -> consecutive addrs)
        for (int j = t; j < total; j += THREADS) {
            int k = bid[j];
            rec[cur[k] + (j - sbase[k])] = make_int2(skey[j], sval[j]);
        }
        __syncthreads();

        for (int k = t; k < nb2; k += THREADS) cur[k] += scur[k] - sbase[k];
        __syncthreads();
    }
}

// ---------------------------------------------------------------------------
// deg partials over ROW half: grid = NB*DM, 256-slot LDS acc, plain writes.
__global__ void degred_kernel(const int2* __restrict__ rec, const int* __restrict__ TU,
                              float* __restrict__ pdeg) {
    __shared__ float acc[BSZ];
    int t = threadIdx.x;
    int bk = blockIdx.x / DM, m = blockIdx.x % DM;
    acc[t] = 0.f;
    __syncthreads();
    int s = TU[bk * SB];
    int e2 = TU[(bk + 1) * SB];
    int len = e2 - s;
    int lo = s + (int)((long long)len * m / DM);
    int hi = s + (int)((long long)len * (m + 1) / DM);
    int i = lo + t;
    for (; i + 3 * THREADS < hi; i += 4 * THREADS) {
        int2 p0 = rec[i];
        int2 p1 = rec[i + THREADS];
        int2 p2 = rec[i + 2 * THREADS];
        int2 p3 = rec[i + 3 * THREADS];
        atomicAdd(&acc[p0.x], __int_as_float(p0.y));
        atomicAdd(&acc[p1.x], __int_as_float(p1.y));
        atomicAdd(&acc[p2.x], __int_as_float(p2.y));
        atomicAdd(&acc[p3.x], __int_as_float(p3.y));
    }
    for (; i < hi; i += THREADS) {
        int2 p = rec[i];
        atomicAdd(&acc[p.x], __int_as_float(p.y));
    }
    __syncthreads();
    pdeg[(size_t)(bk * DM + m) * BSZ + t] = acc[t];
}

// ---------------------------------------------------------------------------
// init (fused deg-partial reduce): dis = rsqrt(sum pdeg); Tx0 = x[:, :2];
// outacc = Tx0 @ Wc[0].
__global__ void init_kernel(const float* __restrict__ x, const float* __restrict__ pdeg,
                            float* __restrict__ dis, float2* __restrict__ tx0,
                            float2* __restrict__ outacc, const float* __restrict__ Wc,
                            int N) {
    int i = blockIdx.x * blockDim.x + threadIdx.x;
    if (i >= N) return;
    int bk = i >> BSH, li = i & BMSK;
    const float* src = pdeg + (size_t)bk * DM * BSZ + li;
    float d = 0.f;
    for (int m = 0; m < DM; ++m) d += src[(size_t)m * BSZ];
    dis[i] = (d > 0.f) ? rsqrtf(d) : 0.f;
    float x0 = x[3 * i + 0];
    float x1 = x[3 * i + 1];
    tx0[i] = make_float2(x0, x1);
    outacc[i] = make_float2(x0 * Wc[0] + x1 * Wc[2],
                            x0 * Wc[1] + x1 * Wc[3]);
}

// ---------------------------------------------------------------------------
// Node-level sort of the COL half + norm baking -> per-node CSR.
// One 1024-thread block per col bucket; sorted {r_global, norm} records land
// in the row-half region of rec (dead after degred).
__global__ void nodesort_kernel(const int2* __restrict__ rec, const int* __restrict__ TU,
                                const float* __restrict__ dis,
                                int2* __restrict__ srec, int* __restrict__ rowstart,
                                int NB, int N) {
    __shared__ int cnt[BSZ], cur[BSZ], stmp[BSZ];
    __shared__ float disc[BSZ];
    int t = threadIdx.x, bk = blockIdx.x;
    int colbase = TU[NB * SB];
    if (t < BSZ) {
        cnt[t] = 0;
        int node = (bk << BSH) + t;
        disc[t] = (node < N) ? dis[node] : 0.f;
    }
    __syncthreads();
    int s = TU[(NB + bk) * SB];
    int e = TU[(NB + bk + 1) * SB];
    for (int i = s + t; i < e; i += 1024) atomicAdd(&cnt[rec[i].x & BMSK], 1);
    __syncthreads();
    if (t < BSZ) stmp[t] = cnt[t];
    __syncthreads();
    for (int d = 1; d < BSZ; d <<= 1) {
        int xv = (t >= d && t < BSZ) ? stmp[t - d] : 0;
        __syncthreads();
        if (t < BSZ) stmp[t] += xv;
        __syncthreads();
    }
    if (t < BSZ) {
        int g = (s - colbase) + stmp[t] - cnt[t];
        cur[t] = g;
        rowstart[(bk << BSH) + t] = g;
        if (bk == NB - 1 && t == 0) rowstart[NB << BSH] = e - colbase;
    }
    __syncthreads();
    for (int i = s + t; i < e; i += 1024) {
        int2 p = rec[i];
        int cl = p.x & BMSK;
        int r = ((unsigned)p.x) >> BSH;
        float w = -dis[r] * __int_as_float(p.y) * disc[cl];
        int pos = atomicAdd(&cur[cl], 1);
        srec[pos] = make_int2(r, __float_as_int(w));
    }
}

// ---------------------------------------------------------------------------
// Propagation with fused Chebyshev update: 16 lanes per node, paired 16B
// nontemporal record loads (2 records / lane), dual accumulators, w16 reduce.
__global__ void gather_kernel(const int2* __restrict__ srec, const int* __restrict__ rowstart,
                              const float2* __restrict__ h, const float2* __restrict__ tx0,
                              float2* __restrict__ vout, float2* __restrict__ outacc,
                              const float* __restrict__ Wc, int k, int N) {
    int g = blockIdx.x * (THREADS / 16) + (threadIdx.x >> 4);
    int lane = threadIdx.x & 15;
    if (g >= N) return;
    int s = rowstart[g];
    int e = rowstart[g + 1];
    float sx0 = 0.f, sy0 = 0.f, sx1 = 0.f, sy1 = 0.f;
    int a = (s + 1) & ~1;                        // first even index >= s
    if ((s & 1) && lane == 15 && s < e) {        // odd head record
        int2 p = srec[s];
        float2 hv = h[p.x];
        float w = __int_as_float(p.y);
        sx0 = fmaf(w, hv.x, sx0); sy0 = fmaf(w, hv.y, sy0);
    }
    for (int i = a + 2 * lane; i < e; i += 32) {
        if (i + 1 < e) {
            int4n v = __builtin_nontemporal_load((const int4n*)(srec + i));
            float w0 = __int_as_float(v.y);
            float w1 = __int_as_float(v.w);
            float2 h0 = h[v.x];
            float2 h1 = h[v.z];
            sx0 = fmaf(w0, h0.x, sx0); sy0 = fmaf(w0, h0.y, sy0);
            sx1 = fmaf(w1, h1.x, sx1); sy1 = fmaf(w1, h1.y, sy1);
        } else {
            int2 p = srec[i];
            float2 hv = h[p.x];
            float w = __int_as_float(p.y);
            sx0 = fmaf(w, hv.x, sx0); sy0 = fmaf(w, hv.y, sy0);
        }
    }
    float sx = sx0 + sx1, sy = sy0 + sy1;
    for (int off = 8; off > 0; off >>= 1) {
        sx += __shfl_down(sx, off, 16);
        sy += __shfl_down(sy, off, 16);
    }
    if (lane == 0) {
        float2 v = make_float2(sx, sy);
        if (tx0) {
            float2 tv = tx0[g];
            v.x = 2.f * v.x - tv.x;
            v.y = 2.f * v.y - tv.y;
        }
        vout[g] = v;
        float2 o = outacc[g];
        o.x += v.x * Wc[4 * k + 0] + v.y * Wc[4 * k + 2];
        o.y += v.x * Wc[4 * k + 1] + v.y * Wc[4 * k + 3];
        outacc[g] = o;
    }
}

// ---------------------------------------------------------------------------
// Full-atomic fallback kernels (only if workspace is too small).
__global__ void zero_kernel(float* __restrict__ p, int n) {
    int i = blockIdx.x * blockDim.x + threadIdx.x;
    if (i < n) p[i] = 0.f;
}
__global__ void zerof2_kernel(float2* __restrict__ p, int n) {
    int i = blockIdx.x * blockDim.x + threadIdx.x;
    if (i < n) p[i] = make_float2(0.f, 0.f);
}
__global__ void deg_at_kernel(const int* __restrict__ row, const int* __restrict__ col,
                              const float* __restrict__ ew, float* __restrict__ deg, int E) {
    int e = blockIdx.x * blockDim.x + threadIdx.x;
    if (e >= E) return;
    int r = row[e], c = col[e];
    if (r != c) atomicAdd(&deg[r], ew[e]);
}
__global__ void init_at_kernel(const float* __restrict__ x, float* __restrict__ deg,
                               float2* __restrict__ tx0, float2* __restrict__ outacc,
                               const float* __restrict__ Wc, int N) {
    int i = blockIdx.x * blockDim.x + threadIdx.x;
    if (i >= N) return;
    float d = deg[i];
    deg[i] = (d > 0.f) ? rsqrtf(d) : 0.f;
    float x0 = x[3 * i + 0];
    float x1 = x[3 * i + 1];
    tx0[i] = make_float2(x0, x1);
    outacc[i] = make_float2(x0 * Wc[0] + x1 * Wc[2],
                            x0 * Wc[1] + x1 * Wc[3]);
}
__global__ void prop_kernel(const int* __restrict__ row, const int* __restrict__ col,
                            const float* __restrict__ ew, const float* __restrict__ dis,
                            const float2* __restrict__ h, float2* __restrict__ o, int E) {
    int e = blockIdx.x * blockDim.x + threadIdx.x;
    if (e >= E) return;
    int r = row[e], c = col[e];
    if (r == c) return;
    float w = -dis[r] * ew[e] * dis[c];
    if (w == 0.f) return;
    float2 hv = h[r];
    atomicAdd(&o[c].x, w * hv.x);
    atomicAdd(&o[c].y, w * hv.y);
}
__global__ void cheb_at_kernel(float2* __restrict__ raw, const float2* __restrict__ tx0,
                               float2* __restrict__ outacc, const float* __restrict__ Wc,
                               int k, int N) {
    int i = blockIdx.x * blockDim.x + threadIdx.x;
    if (i >= N) return;
    float2 v = raw[i];
    if (tx0) {
        float2 t = tx0[i];
        v.x = 2.f * v.x - t.x;
        v.y = 2.f * v.y - t.y;
        raw[i] = v;
    }
    float2 o = outacc[i];
    o.x += v.x * Wc[4 * k + 0] + v.y * Wc[4 * k + 2];
    o.y += v.x * Wc[4 * k + 1] + v.y * Wc[4 * k + 3];
    outacc[i] = o;
}

// ---------------------------------------------------------------------------
// Fused epilogue (3 kernels): per-block (max, sum-of-exp) via LSE rescale.
__global__ void u_ms_kernel(const float* __restrict__ x, const float2* __restrict__ outacc,
                            const float* __restrict__ cb, const float* __restrict__ W,
                            const float* __restrict__ b, float* __restrict__ U,
                            float* __restrict__ part2, int N) {
    __shared__ float sm[THREADS / 64];
    __shared__ float bmax;
    int i = blockIdx.x * blockDim.x + threadIdx.x;
    int t = threadIdx.x;
    float u = -INFINITY;
    if (i < N) {
        float2 o = outacc[i];
        float h0 = fmaxf(o.x + cb[0], 0.f);
        float h1 = fmaxf(o.y + cb[1], 0.f);
        u = x[3 * i + 2] * W[0] + h0 * W[1] + h1 * W[2] + b[0];
        U[i] = u;
    }
    float mv = u;
    for (int off = 32; off > 0; off >>= 1) mv = fmaxf(mv, __shfl_down(mv, off));
    if ((t & 63) == 0) sm[t >> 6] = mv;
    __syncthreads();
    if (t == 0) {
        float m = sm[0];
        for (int w = 1; w < THREADS / 64; ++w) m = fmaxf(m, sm[w]);
        bmax = m;
    }
    __syncthreads();
    float bm = bmax;
    float e = (i < N) ? expf(u - bm) : 0.f;
    for (int off = 32; off > 0; off >>= 1) e += __shfl_down(e, off);
    __syncthreads();
    if ((t & 63) == 0) sm[t >> 6] = e;
    __syncthreads();
    if (t == 0) {
        float s = sm[0];
        for (int w = 1; w < THREADS / 64; ++w) s += sm[w];
        part2[2 * blockIdx.x]     = bm;
        part2[2 * blockIdx.x + 1] = s;
    }
}

__global__ void red_ms_kernel(const float* __restrict__ part2, int n,
                              float* __restrict__ scal) {
    __shared__ float sm[16];
    __shared__ float gmax;
    int t = threadIdx.x;
    float m = -INFINITY;
    for (int i = t; i < n; i += blockDim.x) m = fmaxf(m, part2[2 * i]);
    for (int off = 32; off > 0; off >>= 1) m = fmaxf(m, __shfl_down(m, off));
    int wid = t >> 6;
    if ((t & 63) == 0) sm[wid] = m;
    __syncthreads();
    if (t == 0) {
        float r = sm[0];
        int nw = blockDim.x >> 6;
        for (int w = 1; w < nw; ++w) r = fmaxf(r, sm[w]);
        gmax = r;
    }
    __syncthreads();
    float M = gmax;
    float s = 0.f;
    for (int i = t; i < n; i += blockDim.x) s += part2[2 * i + 1] * expf(part2[2 * i] - M);
    for (int off = 32; off > 0; off >>= 1) s += __shfl_down(s, off);
    __syncthreads();
    if ((t & 63) == 0) sm[wid] = s;
    __syncthreads();
    if (t == 0) {
        float r = sm[0];
        int nw = blockDim.x >> 6;
        for (int w = 1; w < nw; ++w) r += sm[w];
        scal[0] = M;
        scal[1] = 1.f / r;
    }
}

__global__ void out_kernel(const float* __restrict__ U, const float* __restrict__ scal,
                           float* __restrict__ out, int N) {
    int i = blockIdx.x * blockDim.x + threadIdx.x;
    if (i < N) out[i] = expf(U[i] - scal[0]) * scal[1];
}

// ---------------------------------------------------------------------------
extern "C" void kernel_launch(void* const* d_in, const int* in_sizes, int n_in,
                              void* d_out, int out_size, void* d_ws, size_t ws_size,
                              hipStream_t stream) {
    (void)n_in; (void)out_size;
    const float* x    = (const float*)d_in[0];
    const int*   eidx = (const int*)d_in[1];     // int32 per harness contract
    const float* ew   = (const float*)d_in[2];
    const float* Wc   = (const float*)d_in[3];
    const float* cb   = (const float*)d_in[4];
    const float* W    = (const float*)d_in[5];
    const float* b    = (const float*)d_in[6];
    float*       out  = (float*)d_out;

    const int N = in_sizes[0] / 3;
    const int E = in_sizes[2];
    const int K = in_sizes[3] / 4;
    const int* row = eidx;
    const int* col = eidx + E;

    const int NB    = (N + BMSK) >> BSH;         // 256-node buckets
    const int nb2   = 2 * NB;
    const int n2    = nb2 * SB;                  // unified count-table length
    const int nblk  = (n2 + 1023) / 1024;        // scan1 blocks (1024/block)
    const int chunk = (E + SB - 1) / SB;
    const int Npad  = NB << BSH;

    char* ws = (char*)d_ws;
    size_t off = 0;
    auto take = [&](size_t bytes) -> void* {
        void* p = ws + off;
        off = (off + bytes + 255) & ~(size_t)255;
        return p;
    };

    float*  dis      = (float*)take((size_t)N * 4);
    float2* A        = (float2*)take((size_t)N * 8);
    float2* B        = (float2*)take((size_t)N * 8);
    float2* C        = (float2*)take((size_t)N * 8);
    float2* outacc   = (float2*)take((size_t)N * 8);
    float*  U        = (float*)take((size_t)N * 4);
    float*  part     = (float*)take(8192 * 4);
    float*  scal     = (float*)take(64 * 4);
    int*    TU       = (int*)take((size_t)(n2 + 1) * 4);
    int*    bsum     = (int*)take(1024 * 4);
    int*    boff     = (int*)take(1025 * 4);
    int*    rowstart = (int*)take((size_t)(Npad + 1) * 4);
    float*  pdeg     = (float*)take((size_t)NB * DM * BSZ * 4);
    int2*   rec      = (int2*)take((size_t)2 * E * 8);

    const bool bucket_ok = (nb2 <= 1024) && (nblk <= 1024) && (N < (1 << 23)) &&
                           (off <= ws_size);

    const int eb = (E + THREADS - 1) / THREADS;
    const int nb = (N + THREADS - 1) / THREADS;

    if (bucket_ok) {
        // dynamic LDS for scatter (must match device-side layout)
        size_t scat_lds = (size_t)(4 * SEG) * 4      // skey+sval int[2*SEG] each
                        + (size_t)(3 * nb2) * 4      // cur/sbase/scur
                        + 256 * 4                    // stmp
                        + (size_t)(2 * SEG) * 2;     // bid ushort

        hist_kernel<<<SB, THREADS, nb2 * 4, stream>>>(row, col, TU, E, NB, chunk);
        scan1_kernel<<<nblk, 256, 0, stream>>>(TU, bsum, n2);
        scan2_kernel<<<1, 1024, 0, stream>>>(bsum, boff, nblk);
        scan3_kernel<<<(n2 + 256) / 256, 256, 0, stream>>>(TU, boff, n2, nblk);
        scatter_kernel<<<SB, THREADS, scat_lds, stream>>>(row, col, ew, TU, rec, E, NB, chunk);
        degred_kernel<<<NB * DM, THREADS, 0, stream>>>(rec, TU, pdeg);
        init_kernel<<<nb, THREADS, 0, stream>>>(x, pdeg, dis, A, outacc, Wc, N);
        // node-level sort + norm bake; sorted records land in the row half of rec
        nodesort_kernel<<<NB, 1024, 0, stream>>>(rec, TU, dis, rec, rowstart, NB, N);

        const int gb = (N + (THREADS / 16) - 1) / (THREADS / 16);
        // k = 1..K-1, Chebyshev update fused into gather epilogue
        gather_kernel<<<gb, THREADS, 0, stream>>>(rec, rowstart, A, (const float2*)nullptr,
                                                  B, outacc, Wc, 1, N);
        float2 *t0 = A, *t1 = B, *fr = C;
        for (int k = 2; k < K; ++k) {
            gather_kernel<<<gb, THREADS, 0, stream>>>(rec, rowstart, t1, t0, fr, outacc, Wc, k, N);
            float2* n0 = t1; float2* n1 = fr; float2* nf = t0;
            t0 = n0; t1 = n1; fr = nf;
        }
    } else {
        // ---- full-atomic fallback ----
        zero_kernel<<<nb, THREADS, 0, stream>>>(dis, N);
        deg_at_kernel<<<eb, THREADS, 0, stream>>>(row, col, ew, dis, E);
        init_at_kernel<<<nb, THREADS, 0, stream>>>(x, dis, A, outacc, Wc, N);
        zerof2_kernel<<<nb, THREADS, 0, stream>>>(B, N);
        prop_kernel<<<eb, THREADS, 0, stream>>>(row, col, ew, dis, A, B, E);
        cheb_at_kernel<<<nb, THREADS, 0, stream>>>(B, (const float2*)nullptr, outacc, Wc, 1, N);
        float2 *t0 = A, *t1 = B, *fr = C;
        for (int k = 2; k < K; ++k) {
            zerof2_kernel<<<nb, THREADS, 0, stream>>>(fr, N);
            prop_kernel<<<eb, THREADS, 0, stream>>>(row, col, ew, dis, t1, fr, E);
            cheb_at_kernel<<<nb, THREADS, 0, stream>>>(fr, t0, outacc, Wc, k, N);
            float2* n0 = t1; float2* n1 = fr; float2* nf = t0;
            t0 = n0; t1 = n1; fr = nf;
        }
    }

    u_ms_kernel<<<nb, THREADS, 0, stream>>>(x, outacc, cb, W, b, U, part, N);
    red_ms_kernel<<<1, 1024, 0, stream>>>(part, nb, scal);
    out_kernel<<<nb, THREADS, 0, stream>>>(U, scal, out, N);
}

// Round 16
// 371.942 us; speedup vs baseline: 1.2319x; 1.1078x over previous
//
#include <hip/hip_runtime.h>
#include <math.h>

#define THREADS 256
#define SB 1024           // blocks for hist/scatter passes (chunked edge ranges)
#define BSH 8             // bucket shift: 256 nodes per bucket
#define BSZ 256
#define BMSK 255
#define SEG 2048          // edges per scatter segment (8 per thread)

// ---------------------------------------------------------------------------
// Per-block LDS histograms over node buckets (bucket = 256 nodes).
__global__ void hist_kernel(const int* __restrict__ row, const int* __restrict__ col,
                            int* __restrict__ TU, int E, int NB, int chunk) {
    extern __shared__ int sh[];
    int t = threadIdx.x, b = blockIdx.x;
    for (int k = t; k < 2 * NB; k += THREADS) sh[k] = 0;
    __syncthreads();
    int lo = b * chunk;
    int hi = min(lo + chunk, E);
    for (int e = lo + t; e < hi; e += THREADS) {
        int r = row[e], c = col[e];
        if (r != c) {
            atomicAdd(&sh[r >> BSH], 1);
            atomicAdd(&sh[NB + (c >> BSH)], 1);
        }
    }
    __syncthreads();
    for (int k = t; k < 2 * NB; k += THREADS) TU[k * SB + b] = sh[k];
}

// ---------------------------------------------------------------------------
// Exclusive scan, 1024 entries per block (4 serial per thread + block scan).
__global__ void scan1_kernel(int* __restrict__ data, int* __restrict__ bsum, int n) {
    __shared__ int s[256];
    int t = threadIdx.x;
    int base = blockIdx.x * 1024 + t * 4;
    int a0 = (base + 0 < n) ? data[base + 0] : 0;
    int a1 = (base + 1 < n) ? data[base + 1] : 0;
    int a2 = (base + 2 < n) ? data[base + 2] : 0;
    int a3 = (base + 3 < n) ? data[base + 3] : 0;
    int tsum = a0 + a1 + a2 + a3;
    s[t] = tsum;
    __syncthreads();
    for (int d = 1; d < 256; d <<= 1) {
        int xv = (t >= d) ? s[t - d] : 0;
        __syncthreads();
        s[t] += xv;
        __syncthreads();
    }
    int excl = s[t] - tsum;
    if (base + 0 < n) data[base + 0] = excl;
    if (base + 1 < n) data[base + 1] = excl + a0;
    if (base + 2 < n) data[base + 2] = excl + a0 + a1;
    if (base + 3 < n) data[base + 3] = excl + a0 + a1 + a2;
    if (t == 255) bsum[blockIdx.x] = s[255];
}

__global__ void scan2_kernel(const int* __restrict__ bsum, int* __restrict__ boff, int nb) {
    __shared__ int s[1024];
    int t = threadIdx.x;
    int v = (t < nb) ? bsum[t] : 0;
    s[t] = v;
    __syncthreads();
    for (int d = 1; d < 1024; d <<= 1) {
        int xv = (t >= d) ? s[t - d] : 0;
        __syncthreads();
        s[t] += xv;
        __syncthreads();
    }
    if (t < nb) boff[t] = s[t] - v;
    if (t == nb - 1) boff[nb] = s[t];            // grand total
}

__global__ void scan3_kernel(int* __restrict__ data, const int* __restrict__ boff,
                             int n, int nbk) {
    int i = blockIdx.x * blockDim.x + threadIdx.x;
    if (i < n) data[i] += boff[i >> 10];
    else if (i == n) data[n] = boff[nbk];        // append grand total
}

// ---------------------------------------------------------------------------
// Scatter with segment-local counting sort (r10 measured-best variant:
// SEG=2048, AoS int2 staging + ushort bid, dense line-filling write-out).
__global__ void scatter_kernel(const int* __restrict__ row, const int* __restrict__ col,
                               const float* __restrict__ ew,
                               const int* __restrict__ TU, int2* __restrict__ rec,
                               int E, int NB, int chunk) {
    extern __shared__ int shl[];
    const int nb2 = 2 * NB;                                    // <= 1024
    int2* staged = (int2*)shl;                                 // [2*SEG]
    int* cur   = shl + 4 * SEG;                                // [nb2]
    int* sbase = cur + nb2;                                    // [nb2]
    int* scur  = sbase + nb2;                                  // [nb2]
    int* stmp  = scur + nb2;                                   // [256]
    unsigned short* bid = (unsigned short*)(stmp + 256);       // [2*SEG]

    int t = threadIdx.x, b = blockIdx.x;
    for (int k = t; k < nb2; k += THREADS) cur[k] = TU[k * SB + b];
    int lo = b * chunk;
    int hi = min(lo + chunk, E);

    for (int slo = lo; slo < hi; slo += SEG) {
        int scount = min(SEG, hi - slo);
        for (int k = t; k < nb2; k += THREADS) sbase[k] = 0;
        __syncthreads();

        int er[8], ec[8];
        float ewv[8];
#pragma unroll
        for (int j = 0; j < 8; ++j) {
            er[j] = -1;
            int e = slo + j * THREADS + t;
            if (e < slo + scount) {
                int r = row[e], c = col[e];
                if (r != c) {
                    er[j] = r; ec[j] = c; ewv[j] = ew[e];
                    atomicAdd(&sbase[r >> BSH], 1);
                    atomicAdd(&sbase[NB + (c >> BSH)], 1);
                }
            }
        }
        __syncthreads();

        // exclusive scan of nb2 per-bucket counts (4 serial + 256 block scan)
        int b4 = t * 4;
        int a0 = (b4 + 0 < nb2) ? sbase[b4 + 0] : 0;
        int a1 = (b4 + 1 < nb2) ? sbase[b4 + 1] : 0;
        int a2 = (b4 + 2 < nb2) ? sbase[b4 + 2] : 0;
        int a3 = (b4 + 3 < nb2) ? sbase[b4 + 3] : 0;
        int tsum = a0 + a1 + a2 + a3;
        stmp[t] = tsum;
        __syncthreads();
        for (int d = 1; d < 256; d <<= 1) {
            int xv = (t >= d) ? stmp[t - d] : 0;
            __syncthreads();
            stmp[t] += xv;
            __syncthreads();
        }
        int excl = stmp[t] - tsum;
        int total = stmp[255];
        __syncthreads();
        if (b4 + 0 < nb2) { sbase[b4 + 0] = excl;                scur[b4 + 0] = excl; }
        if (b4 + 1 < nb2) { sbase[b4 + 1] = excl + a0;           scur[b4 + 1] = excl + a0; }
        if (b4 + 2 < nb2) { sbase[b4 + 2] = excl + a0 + a1;      scur[b4 + 2] = excl + a0 + a1; }
        if (b4 + 3 < nb2) { sbase[b4 + 3] = excl + a0 + a1 + a2; scur[b4 + 3] = excl + a0 + a1 + a2; }
        __syncthreads();

        // ranked placement into bucket-ordered staging
#pragma unroll
        for (int j = 0; j < 8; ++j) {
            if (er[j] >= 0) {
                int r = er[j], c = ec[j];
                int wbits = __float_as_int(ewv[j]);
                int k1 = r >> BSH;
                int p1 = atomicAdd(&scur[k1], 1);
                staged[p1] = make_int2(r & BMSK, wbits);
                bid[p1] = (unsigned short)k1;
                int k2 = NB + (c >> BSH);
                int p2 = atomicAdd(&scur[k2], 1);
                staged[p2] = make_int2((r << BSH) | (c & BMSK), wbits);
                bid[p2] = (unsigned short)k2;
            }
        }
        __syncthreads();

        // cooperative dense write-out (consecutive lanes -> consecutive addrs)
        for (int j = t; j < total; j += THREADS) {
            int k = bid[j];
            rec[cur[k] + (j - sbase[k])] = staged[j];
        }
        __syncthreads();

        for (int k = t; k < nb2; k += THREADS) cur[k] += scur[k] - sbase[k];
        __syncthreads();
    }
}

// ---------------------------------------------------------------------------
// Fused deg-reduce + init: one 1024-thread block per bucket streams the
// bucket's ROW-half records into LDS acc, then finalizes dis/tx0/outacc for
// its 256 nodes. Eliminates the pdeg HBM round-trip.
__global__ void degini_kernel(const int2* __restrict__ rec, const int* __restrict__ TU,
                              const float* __restrict__ x,
                              float* __restrict__ dis, float2* __restrict__ tx0,
                              float2* __restrict__ outacc, const float* __restrict__ Wc,
                              int N) {
    __shared__ float acc[BSZ];
    int t = threadIdx.x, bk = blockIdx.x;
    if (t < BSZ) acc[t] = 0.f;
    __syncthreads();
    int s = TU[bk * SB];
    int e = TU[(bk + 1) * SB];
    int i = s + t;
    for (; i + 3 * 1024 < e; i += 4 * 1024) {
        int2 p0 = rec[i];
        int2 p1 = rec[i + 1024];
        int2 p2 = rec[i + 2048];
        int2 p3 = rec[i + 3072];
        atomicAdd(&acc[p0.x], __int_as_float(p0.y));
        atomicAdd(&acc[p1.x], __int_as_float(p1.y));
        atomicAdd(&acc[p2.x], __int_as_float(p2.y));
        atomicAdd(&acc[p3.x], __int_as_float(p3.y));
    }
    for (; i < e; i += 1024) {
        int2 p = rec[i];
        atomicAdd(&acc[p.x], __int_as_float(p.y));
    }
    __syncthreads();
    if (t < BSZ) {
        int node = (bk << BSH) + t;
        if (node < N) {
            float d = acc[t];
            dis[node] = (d > 0.f) ? rsqrtf(d) : 0.f;
            float x0 = x[3 * node + 0];
            float x1 = x[3 * node + 1];
            tx0[node] = make_float2(x0, x1);
            outacc[node] = make_float2(x0 * Wc[0] + x1 * Wc[2],
                                       x0 * Wc[1] + x1 * Wc[3]);
        }
    }
}

// ---------------------------------------------------------------------------
// Node-level sort of the COL half + norm baking + FUSED PASS-1 PROPAGATION.
// One 1024-thread block per col bucket. The placement loop already holds
// (r, w) per record, so Tx1 = S·Tx0 accumulates into LDS for free; the k=1
// Chebyshev update runs in the epilogue. Sorted {r_global, norm} records
// land in the row-half region of rec (dead after degini).
__global__ void nodesort_kernel(const int2* __restrict__ rec, const int* __restrict__ TU,
                                const float* __restrict__ dis, const float2* __restrict__ hA,
                                int2* __restrict__ srec, int* __restrict__ rowstart,
                                float2* __restrict__ vout, float2* __restrict__ outacc,
                                const float* __restrict__ Wc, int NB, int N) {
    __shared__ int cnt[BSZ], cur[BSZ], stmp[BSZ];
    __shared__ float disc[BSZ], ax[BSZ], ay[BSZ];
    int t = threadIdx.x, bk = blockIdx.x;
    int colbase = TU[NB * SB];
    if (t < BSZ) {
        cnt[t] = 0;
        ax[t] = 0.f;
        ay[t] = 0.f;
        int node = (bk << BSH) + t;
        disc[t] = (node < N) ? dis[node] : 0.f;
    }
    __syncthreads();
    int s = TU[(NB + bk) * SB];
    int e = TU[(NB + bk + 1) * SB];
    for (int i = s + t; i < e; i += 1024) atomicAdd(&cnt[rec[i].x & BMSK], 1);
    __syncthreads();
    if (t < BSZ) stmp[t] = cnt[t];
    __syncthreads();
    for (int d = 1; d < BSZ; d <<= 1) {
        int xv = (t >= d && t < BSZ) ? stmp[t - d] : 0;
        __syncthreads();
        if (t < BSZ) stmp[t] += xv;
        __syncthreads();
    }
    if (t < BSZ) {
        int g = (s - colbase) + stmp[t] - cnt[t];
        cur[t] = g;
        rowstart[(bk << BSH) + t] = g;
        if (bk == NB - 1 && t == 0) rowstart[NB << BSH] = e - colbase;
    }
    __syncthreads();
    for (int i = s + t; i < e; i += 1024) {
        int2 p = rec[i];
        int cl = p.x & BMSK;
        int r = ((unsigned)p.x) >> BSH;
        float w = -dis[r] * __int_as_float(p.y) * disc[cl];
        int pos = atomicAdd(&cur[cl], 1);
        srec[pos] = make_int2(r, __float_as_int(w));
        float2 hv = hA[r];
        atomicAdd(&ax[cl], w * hv.x);
        atomicAdd(&ay[cl], w * hv.y);
    }
    __syncthreads();
    if (t < BSZ) {
        int node = (bk << BSH) + t;
        if (node < N) {
            float2 v = make_float2(ax[t], ay[t]);       // Tx1 (k=1: no recurrence)
            vout[node] = v;
            float2 o = outacc[node];
            o.x += v.x * Wc[4 + 0] + v.y * Wc[4 + 2];   // Wc[1]
            o.y += v.x * Wc[4 + 1] + v.y * Wc[4 + 3];
            outacc[node] = o;
        }
    }
}

// ---------------------------------------------------------------------------
// Propagation with fused Chebyshev update (k>=2): 16 lanes per node, simple
// strided record loop (measured-best r11 form), width-16 shuffle reduce.
__global__ void gather_kernel(const int2* __restrict__ srec, const int* __restrict__ rowstart,
                              const float2* __restrict__ h, const float2* __restrict__ tx0,
                              float2* __restrict__ vout, float2* __restrict__ outacc,
                              const float* __restrict__ Wc, int k, int N) {
    int g = blockIdx.x * (THREADS / 16) + (threadIdx.x >> 4);
    int lane = threadIdx.x & 15;
    if (g >= N) return;
    int s = rowstart[g];
    int e = rowstart[g + 1];
    float sx = 0.f, sy = 0.f;
    for (int i = s + lane; i < e; i += 16) {
        int2 p = srec[i];
        float2 hv = h[p.x];
        float w = __int_as_float(p.y);
        sx = fmaf(w, hv.x, sx);
        sy = fmaf(w, hv.y, sy);
    }
    for (int off = 8; off > 0; off >>= 1) {
        sx += __shfl_down(sx, off, 16);
        sy += __shfl_down(sy, off, 16);
    }
    if (lane == 0) {
        float2 v = make_float2(sx, sy);
        if (tx0) {
            float2 tv = tx0[g];
            v.x = 2.f * v.x - tv.x;
            v.y = 2.f * v.y - tv.y;
        }
        vout[g] = v;
        float2 o = outacc[g];
        o.x += v.x * Wc[4 * k + 0] + v.y * Wc[4 * k + 2];
        o.y += v.x * Wc[4 * k + 1] + v.y * Wc[4 * k + 3];
        outacc[g] = o;
    }
}

// ---------------------------------------------------------------------------
// Full-atomic fallback kernels (only if workspace is too small).
__global__ void zero_kernel(float* __restrict__ p, int n) {
    int i = blockIdx.x * blockDim.x + threadIdx.x;
    if (i < n) p[i] = 0.f;
}
__global__ void zerof2_kernel(float2* __restrict__ p, int n) {
    int i = blockIdx.x * blockDim.x + threadIdx.x;
    if (i < n) p[i] = make_float2(0.f, 0.f);
}
__global__ void deg_at_kernel(const int* __restrict__ row, const int* __restrict__ col,
                              const float* __restrict__ ew, float* __restrict__ deg, int E) {
    int e = blockIdx.x * blockDim.x + threadIdx.x;
    if (e >= E) return;
    int r = row[e], c = col[e];
    if (r != c) atomicAdd(&deg[r], ew[e]);
}
__global__ void init_at_kernel(const float* __restrict__ x, float* __restrict__ deg,
                               float2* __restrict__ tx0, float2* __restrict__ outacc,
                               const float* __restrict__ Wc, int N) {
    int i = blockIdx.x * blockDim.x + threadIdx.x;
    if (i >= N) return;
    float d = deg[i];
    deg[i] = (d > 0.f) ? rsqrtf(d) : 0.f;
    float x0 = x[3 * i + 0];
    float x1 = x[3 * i + 1];
    tx0[i] = make_float2(x0, x1);
    outacc[i] = make_float2(x0 * Wc[0] + x1 * Wc[2],
                            x0 * Wc[1] + x1 * Wc[3]);
}
__global__ void prop_kernel(const int* __restrict__ row, const int* __restrict__ col,
                            const float* __restrict__ ew, const float* __restrict__ dis,
                            const float2* __restrict__ h, float2* __restrict__ o, int E) {
    int e = blockIdx.x * blockDim.x + threadIdx.x;
    if (e >= E) return;
    int r = row[e], c = col[e];
    if (r == c) return;
    float w = -dis[r] * ew[e] * dis[c];
    if (w == 0.f) return;
    float2 hv = h[r];
    atomicAdd(&o[c].x, w * hv.x);
    atomicAdd(&o[c].y, w * hv.y);
}
__global__ void cheb_at_kernel(float2* __restrict__ raw, const float2* __restrict__ tx0,
                               float2* __restrict__ outacc, const float* __restrict__ Wc,
                               int k, int N) {
    int i = blockIdx.x * blockDim.x + threadIdx.x;
    if (i >= N) return;
    float2 v = raw[i];
    if (tx0) {
        float2 t = tx0[i];
        v.x = 2.f * v.x - t.x;
        v.y = 2.f * v.y - t.y;
        raw[i] = v;
    }
    float2 o = outacc[i];
    o.x += v.x * Wc[4 * k + 0] + v.y * Wc[4 * k + 2];
    o.y += v.x * Wc[4 * k + 1] + v.y * Wc[4 * k + 3];
    outacc[i] = o;
}

// ---------------------------------------------------------------------------
// Fused epilogue (3 kernels): per-block (max, sum-of-exp) via LSE rescale.
__global__ void u_ms_kernel(const float* __restrict__ x, const float2* __restrict__ outacc,
                            const float* __restrict__ cb, const float* __restrict__ W,
                            const float* __restrict__ b, float* __restrict__ U,
                            float* __restrict__ part2, int N) {
    __shared__ float sm[THREADS / 64];
    __shared__ float bmax;
    int i = blockIdx.x * blockDim.x + threadIdx.x;
    int t = threadIdx.x;
    float u = -INFINITY;
    if (i < N) {
        float2 o = outacc[i];
        float h0 = fmaxf(o.x + cb[0], 0.f);
        float h1 = fmaxf(o.y + cb[1], 0.f);
        u = x[3 * i + 2] * W[0] + h0 * W[1] + h1 * W[2] + b[0];
        U[i] = u;
    }
    float mv = u;
    for (int off = 32; off > 0; off >>= 1) mv = fmaxf(mv, __shfl_down(mv, off));
    if ((t & 63) == 0) sm[t >> 6] = mv;
    __syncthreads();
    if (t == 0) {
        float m = sm[0];
        for (int w = 1; w < THREADS / 64; ++w) m = fmaxf(m, sm[w]);
        bmax = m;
    }
    __syncthreads();
    float bm = bmax;
    float e = (i < N) ? expf(u - bm) : 0.f;
    for (int off = 32; off > 0; off >>= 1) e += __shfl_down(e, off);
    __syncthreads();
    if ((t & 63) == 0) sm[t >> 6] = e;
    __syncthreads();
    if (t == 0) {
        float s = sm[0];
        for (int w = 1; w < THREADS / 64; ++w) s += sm[w];
        part2[2 * blockIdx.x]     = bm;
        part2[2 * blockIdx.x + 1] = s;
    }
}

__global__ void red_ms_kernel(const float* __restrict__ part2, int n,
                              float* __restrict__ scal) {
    __shared__ float sm[16];
    __shared__ float gmax;
    int t = threadIdx.x;
    float m = -INFINITY;
    for (int i = t; i < n; i += blockDim.x) m = fmaxf(m, part2[2 * i]);
    for (int off = 32; off > 0; off >>= 1) m = fmaxf(m, __shfl_down(m, off));
    int wid = t >> 6;
    if ((t & 63) == 0) sm[wid] = m;
    __syncthreads();
    if (t == 0) {
        float r = sm[0];
        int nw = blockDim.x >> 6;
        for (int w = 1; w < nw; ++w) r = fmaxf(r, sm[w]);
        gmax = r;
    }
    __syncthreads();
    float M = gmax;
    float s = 0.f;
    for (int i = t; i < n; i += blockDim.x) s += part2[2 * i + 1] * expf(part2[2 * i] - M);
    for (int off = 32; off > 0; off >>= 1) s += __shfl_down(s, off);
    __syncthreads();
    if ((t & 63) == 0) sm[wid] = s;
    __syncthreads();
    if (t == 0) {
        float r = sm[0];
        int nw = blockDim.x >> 6;
        for (int w = 1; w < nw; ++w) r += sm[w];
        scal[0] = M;
        scal[1] = 1.f / r;
    }
}

__global__ void out_kernel(const float* __restrict__ U, const float* __restrict__ scal,
                           float* __restrict__ out, int N) {
    int i = blockIdx.x * blockDim.x + threadIdx.x;
    if (i < N) out[i] = expf(U[i] - scal[0]) * scal[1];
}

// ---------------------------------------------------------------------------
extern "C" void kernel_launch(void* const* d_in, const int* in_sizes, int n_in,
                              void* d_out, int out_size, void* d_ws, size_t ws_size,
                              hipStream_t stream) {
    (void)n_in; (void)out_size;
    const float* x    = (const float*)d_in[0];
    const int*   eidx = (const int*)d_in[1];     // int32 per harness contract
    const float* ew   = (const float*)d_in[2];
    const float* Wc   = (const float*)d_in[3];
    const float* cb   = (const float*)d_in[4];
    const float* W    = (const float*)d_in[5];
    const float* b    = (const float*)d_in[6];
    float*       out  = (float*)d_out;

    const int N = in_sizes[0] / 3;
    const int E = in_sizes[2];
    const int K = in_sizes[3] / 4;
    const int* row = eidx;
    const int* col = eidx + E;

    const int NB    = (N + BMSK) >> BSH;         // 256-node buckets
    const int nb2   = 2 * NB;
    const int n2    = nb2 * SB;                  // unified count-table length
    const int nblk  = (n2 + 1023) / 1024;        // scan1 blocks (1024/block)
    const int chunk = (E + SB - 1) / SB;
    const int Npad  = NB << BSH;

    char* ws = (char*)d_ws;
    size_t off = 0;
    auto take = [&](size_t bytes) -> void* {
        void* p = ws + off;
        off = (off + bytes + 255) & ~(size_t)255;
        return p;
    };

    float*  dis      = (float*)take((size_t)N * 4);
    float2* A        = (float2*)take((size_t)N * 8);
    float2* B        = (float2*)take((size_t)N * 8);
    float2* C        = (float2*)take((size_t)N * 8);
    float2* outacc   = (float2*)take((size_t)N * 8);
    float*  U        = (float*)take((size_t)N * 4);
    float*  part     = (float*)take(8192 * 4);
    float*  scal     = (float*)take(64 * 4);
    int*    TU       = (int*)take((size_t)(n2 + 1) * 4);
    int*    bsum     = (int*)take(1024 * 4);
    int*    boff     = (int*)take(1025 * 4);
    int*    rowstart = (int*)take((size_t)(Npad + 1) * 4);
    int2*   rec      = (int2*)take((size_t)2 * E * 8);

    const bool bucket_ok = (nb2 <= 1024) && (nblk <= 1024) && (N < (1 << 23)) &&
                           (off <= ws_size) && (K >= 2);

    const int eb = (E + THREADS - 1) / THREADS;
    const int nb = (N + THREADS - 1) / THREADS;

    if (bucket_ok) {
        // dynamic LDS for scatter (must match device-side layout)
        size_t scat_lds = (size_t)(4 * SEG) * 4      // staged int2[2*SEG]
                        + (size_t)(3 * nb2) * 4      // cur/sbase/scur
                        + 256 * 4                    // stmp
                        + (size_t)(2 * SEG) * 2;     // bid ushort

        hist_kernel<<<SB, THREADS, nb2 * 4, stream>>>(row, col, TU, E, NB, chunk);
        scan1_kernel<<<nblk, 256, 0, stream>>>(TU, bsum, n2);
        scan2_kernel<<<1, 1024, 0, stream>>>(bsum, boff, nblk);
        scan3_kernel<<<(n2 + 256) / 256, 256, 0, stream>>>(TU, boff, n2, nblk);
        scatter_kernel<<<SB, THREADS, scat_lds, stream>>>(row, col, ew, TU, rec, E, NB, chunk);
        // fused deg-reduce + init (row half)
        degini_kernel<<<NB, 1024, 0, stream>>>(rec, TU, x, dis, A, outacc, Wc, N);
        // node sort + norm bake + fused pass-1 prop + cheb k=1 (col half -> row-half region)
        nodesort_kernel<<<NB, 1024, 0, stream>>>(rec, TU, dis, A, rec, rowstart,
                                                 B, outacc, Wc, NB, N);

        const int gb = (N + (THREADS / 16) - 1) / (THREADS / 16);
        // k = 2..K-1, Chebyshev update fused into gather epilogue
        float2 *t0 = A, *t1 = B, *fr = C;
        for (int k = 2; k < K; ++k) {
            gather_kernel<<<gb, THREADS, 0, stream>>>(rec, rowstart, t1, t0, fr, outacc, Wc, k, N);
            float2* n0 = t1; float2* n1 = fr; float2* nf = t0;
            t0 = n0; t1 = n1; fr = nf;
        }
    } else {
        // ---- full-atomic fallback ----
        zero_kernel<<<nb, THREADS, 0, stream>>>(dis, N);
        deg_at_kernel<<<eb, THREADS, 0, stream>>>(row, col, ew, dis, E);
        init_at_kernel<<<nb, THREADS, 0, stream>>>(x, dis, A, outacc, Wc, N);
        zerof2_kernel<<<nb, THREADS, 0, stream>>>(B, N);
        prop_kernel<<<eb, THREADS, 0, stream>>>(row, col, ew, dis, A, B, E);
        cheb_at_kernel<<<nb, THREADS, 0, stream>>>(B, (const float2*)nullptr, outacc, Wc, 1, N);
        float2 *t0 = A, *t1 = B, *fr = C;
        for (int k = 2; k < K; ++k) {
            zerof2_kernel<<<nb, THREADS, 0, stream>>>(fr, N);
            prop_kernel<<<eb, THREADS, 0, stream>>>(row, col, ew, dis, t1, fr, E);
            cheb_at_kernel<<<nb, THREADS, 0, stream>>>(fr, t0, outacc, Wc, k, N);
            float2* n0 = t1; float2* n1 = fr; float2* nf = t0;
            t0 = n0; t1 = n1; fr = nf;
        }
    }

    u_ms_kernel<<<nb, THREADS, 0, stream>>>(x, outacc, cb, W, b, U, part, N);
    red_ms_kernel<<<1, 1024, 0, stream>>>(part, nb, scal);
    out_kernel<<<nb, THREADS, 0, stream>>>(U, scal, out, N);
}